// Round 1
// baseline (1118.344 us; speedup 1.0000x reference)
//
#include <hip/hip_runtime.h>

// LightGCN propagation on MI355X.
// N = 524288 nodes, D = 64, NNZ = 1.25M, 3 layers, mean over 4 states.
// Memory-bound + scatter-atomic-bound; no MFMA path (f32 scatter).

constexpr int NUM_USER = 262144;
constexpr int NUM_ITEM = 262144;
constexpr int DIM      = 64;
constexpr int N_NODES  = NUM_USER + NUM_ITEM;
constexpr int NNZ      = 1250000;
constexpr int N_LAYERS = 3;

// ego = concat(user_emb, item_emb); write it to cur (ws) and acc (d_out).
__global__ void lgcn_init(const float4* __restrict__ ue,
                          const float4* __restrict__ ie,
                          float4* __restrict__ cur,
                          float4* __restrict__ acc) {
    const long total  = (long)N_NODES * (DIM / 4);
    const long utotal = (long)NUM_USER * (DIM / 4);
    long i = (long)blockIdx.x * blockDim.x + threadIdx.x;
    const long stride = (long)gridDim.x * blockDim.x;
    for (; i < total; i += stride) {
        float4 v = (i < utotal) ? ue[i] : ie[i - utotal];
        cur[i] = v;
        acc[i] = v;
    }
}

// y[rows[e]] += vals[e] * x[cols[e]]  — 64 lanes per edge, lane d owns dim d.
// Grid-stride is a multiple of 64 so each wave stays edge-aligned:
// rows/cols/vals loads are wave-uniform, gather/atomic are 256B coalesced.
__global__ void lgcn_spmm(const int*   __restrict__ rows,
                          const int*   __restrict__ cols,
                          const float* __restrict__ vals,
                          const float* __restrict__ x,
                          float*       __restrict__ y) {
    const long total  = (long)NNZ * DIM;
    long t = (long)blockIdx.x * blockDim.x + threadIdx.x;
    const long stride = (long)gridDim.x * blockDim.x;  // 2048*256, % 64 == 0
    for (; t < total; t += stride) {
        const int   e = (int)(t >> 6);
        const int   d = (int)(t & 63);
        const int   r = rows[e];
        const int   c = cols[e];
        const float v = vals[e];
        atomicAdd(&y[((long)r << 6) + d], v * x[((long)c << 6) + d]);
    }
}

// acc = (acc + nxt) * scale   (scale = 1.0 mid-layers, 0.25 on the last)
__global__ void lgcn_add(float4* __restrict__ acc,
                         const float4* __restrict__ nxt,
                         float scale) {
    const long total  = (long)N_NODES * (DIM / 4);
    long i = (long)blockIdx.x * blockDim.x + threadIdx.x;
    const long stride = (long)gridDim.x * blockDim.x;
    for (; i < total; i += stride) {
        float4 a = acc[i];
        const float4 b = nxt[i];
        a.x = (a.x + b.x) * scale;
        a.y = (a.y + b.y) * scale;
        a.z = (a.z + b.z) * scale;
        a.w = (a.w + b.w) * scale;
        acc[i] = a;
    }
}

extern "C" void kernel_launch(void* const* d_in, const int* in_sizes, int n_in,
                              void* d_out, int out_size, void* d_ws, size_t ws_size,
                              hipStream_t stream) {
    const float* ue   = (const float*)d_in[0];
    const float* ie   = (const float*)d_in[1];
    const int*   rows = (const int*)d_in[2];
    const int*   cols = (const int*)d_in[3];
    const float* vals = (const float*)d_in[4];

    float* acc  = (float*)d_out;                       // running sum -> mean
    float* buf0 = (float*)d_ws;                        // 134.2 MB
    float* buf1 = buf0 + (size_t)N_NODES * DIM;        // 134.2 MB

    lgcn_init<<<4096, 256, 0, stream>>>((const float4*)ue, (const float4*)ie,
                                        (float4*)buf0, (float4*)acc);

    float* cur = buf0;
    float* nxt = buf1;
    const size_t bufBytes = (size_t)N_NODES * DIM * sizeof(float);
    for (int l = 0; l < N_LAYERS; ++l) {
        hipMemsetAsync(nxt, 0, bufBytes, stream);
        lgcn_spmm<<<2048, 256, 0, stream>>>(rows, cols, vals, cur, nxt);
        const float scale = (l == N_LAYERS - 1) ? (1.0f / (N_LAYERS + 1)) : 1.0f;
        lgcn_add<<<4096, 256, 0, stream>>>((float4*)acc, (const float4*)nxt, scale);
        float* t = cur; cur = nxt; nxt = t;
    }
}

// Round 2
// 1051.386 us; speedup vs baseline: 1.0637x; 1.0637x over previous
//
#include <hip/hip_runtime.h>

// LightGCN propagation on MI355X — CSR-on-device formulation.
// N = 524288 nodes, D = 64, NNZ = 1.25M, 3 layers, mean over 4 states.
// R1 showed edge-parallel atomicAdd = 320MB HBM RMW per layer (every 256B
// atomic line misses L2). Fix: build CSR once (atomics confined to a 2MB
// L2-resident counter array), then atomic-free row-parallel SpMM with the
// accumulate pass and final scale fused in, and no memsets at all.

constexpr int NUM_USER = 262144;
constexpr int NUM_ITEM = 262144;
constexpr int DIM      = 64;
constexpr int N_NODES  = NUM_USER + NUM_ITEM;   // 524288
constexpr int NNZ      = 1250000;
constexpr int N_LAYERS = 3;
constexpr int SCAN_BLOCKS = N_NODES / 256;      // 2048

// ---------------- init: ego = concat(ue, ie) -> cur and acc ----------------
__global__ void lgcn_init(const float4* __restrict__ ue,
                          const float4* __restrict__ ie,
                          float4* __restrict__ cur,
                          float4* __restrict__ acc) {
    const long total  = (long)N_NODES * (DIM / 4);
    const long utotal = (long)NUM_USER * (DIM / 4);
    long i = (long)blockIdx.x * blockDim.x + threadIdx.x;
    const long stride = (long)gridDim.x * blockDim.x;
    for (; i < total; i += stride) {
        float4 v = (i < utotal) ? ue[i] : ie[i - utotal];
        cur[i] = v;
        acc[i] = v;
    }
}

// ---------------- CSR build ----------------
__global__ void hist_rows(const int* __restrict__ rows, int* __restrict__ counts) {
    int i = blockIdx.x * blockDim.x + threadIdx.x;
    const int stride = gridDim.x * blockDim.x;
    for (; i < NNZ; i += stride) atomicAdd(&counts[rows[i]], 1);
}

// per-256-block exclusive scan in place + block totals
__global__ void scan_block(int* __restrict__ data, int* __restrict__ partials) {
    __shared__ int tmp[256];
    const int t = threadIdx.x;
    const int i = blockIdx.x * 256 + t;
    const int v = data[i];
    tmp[t] = v;
    __syncthreads();
    for (int off = 1; off < 256; off <<= 1) {
        int x = (t >= off) ? tmp[t - off] : 0;
        __syncthreads();
        tmp[t] += x;
        __syncthreads();
    }
    data[i] = tmp[t] - v;                       // exclusive within block
    if (t == 255) partials[blockIdx.x] = tmp[255];
}

// exclusive scan of the 2048 block totals (single block, 8 elems/thread)
__global__ void scan_partials(int* __restrict__ p) {
    __shared__ int tmp[256];
    const int t = threadIdx.x;
    int loc[8];
    #pragma unroll
    for (int k = 0; k < 8; ++k) loc[k] = p[t * 8 + k];
    int run = 0;
    #pragma unroll
    for (int k = 0; k < 8; ++k) { int v = loc[k]; loc[k] = run; run += v; }
    tmp[t] = run;
    __syncthreads();
    for (int off = 1; off < 256; off <<= 1) {
        int x = (t >= off) ? tmp[t - off] : 0;
        __syncthreads();
        tmp[t] += x;
        __syncthreads();
    }
    const int excl = tmp[t] - run;
    #pragma unroll
    for (int k = 0; k < 8; ++k) p[t * 8 + k] = loc[k] + excl;
}

// row_ptr = blockscan + partials; cursor = copy; row_ptr[N] = NNZ
__global__ void add_offsets(int* __restrict__ rp, int* __restrict__ cursor,
                            const int* __restrict__ partials) {
    const int i = blockIdx.x * 256 + threadIdx.x;
    const int v = rp[i] + partials[blockIdx.x];
    rp[i] = v;
    cursor[i] = v;
    if (i == 0) rp[N_NODES] = NNZ;
}

// sorted (col, val) pairs; atomics hit the 2MB L2-resident cursor array only
__global__ void scatter_edges(const int* __restrict__ rows, const int* __restrict__ cols,
                              const float* __restrict__ vals, int* __restrict__ cursor,
                              int2* __restrict__ sc) {
    int i = blockIdx.x * blockDim.x + threadIdx.x;
    const int stride = gridDim.x * blockDim.x;
    for (; i < NNZ; i += stride) {
        const int pos = atomicAdd(&cursor[rows[i]], 1);
        sc[pos] = make_int2(cols[i], __float_as_int(vals[i]));
    }
}

// ---------------- atomic-free SpMM, one wave per row, fused acc update ------
__global__ void spmm_csr(const int* __restrict__ ptr, const int2* __restrict__ sc,
                         const float* __restrict__ x, float* __restrict__ nxt,
                         float* __restrict__ acc, float scale, int write_nxt) {
    const int row = blockIdx.x * 4 + (threadIdx.x >> 6);
    const int d   = threadIdx.x & 63;
    const int beg = ptr[row];
    const int end = ptr[row + 1];
    float s = 0.f;
    for (int e = beg; e < end; ++e) {
        const int2 cv = sc[e];                          // wave-uniform
        s += __int_as_float(cv.y) * x[((long)cv.x << 6) + d];
    }
    const long o = ((long)row << 6) + d;
    if (write_nxt) nxt[o] = s;
    acc[o] = (acc[o] + s) * scale;
}

// ---------------- fallback (round-1 proven path) ----------------
__global__ void lgcn_spmm_atomic(const int* __restrict__ rows, const int* __restrict__ cols,
                                 const float* __restrict__ vals, const float* __restrict__ x,
                                 float* __restrict__ y) {
    const long total  = (long)NNZ * DIM;
    long t = (long)blockIdx.x * blockDim.x + threadIdx.x;
    const long stride = (long)gridDim.x * blockDim.x;
    for (; t < total; t += stride) {
        const int e = (int)(t >> 6);
        const int d = (int)(t & 63);
        atomicAdd(&y[((long)rows[e] << 6) + d], vals[e] * x[((long)cols[e] << 6) + d]);
    }
}

__global__ void lgcn_add(float4* __restrict__ acc, const float4* __restrict__ nxt, float scale) {
    const long total  = (long)N_NODES * (DIM / 4);
    long i = (long)blockIdx.x * blockDim.x + threadIdx.x;
    const long stride = (long)gridDim.x * blockDim.x;
    for (; i < total; i += stride) {
        float4 a = acc[i];
        const float4 b = nxt[i];
        a.x = (a.x + b.x) * scale;
        a.y = (a.y + b.y) * scale;
        a.z = (a.z + b.z) * scale;
        a.w = (a.w + b.w) * scale;
        acc[i] = a;
    }
}

extern "C" void kernel_launch(void* const* d_in, const int* in_sizes, int n_in,
                              void* d_out, int out_size, void* d_ws, size_t ws_size,
                              hipStream_t stream) {
    const float* ue   = (const float*)d_in[0];
    const float* ie   = (const float*)d_in[1];
    const int*   rows = (const int*)d_in[2];
    const int*   cols = (const int*)d_in[3];
    const float* vals = (const float*)d_in[4];
    float* acc = (float*)d_out;

    const size_t embBytes = (size_t)N_NODES * DIM * sizeof(float);   // 134,217,728
    char* ws = (char*)d_ws;
    float* buf0 = (float*)ws;                                        // cur
    float* buf1 = (float*)(ws + embBytes);                           // nxt
    // CSR region (8B-aligned: 2*embBytes % 8 == 0)
    int2* sc      = (int2*)(ws + 2 * embBytes);                      // 10,000,000 B
    int*  row_ptr = (int*)((char*)sc + (size_t)NNZ * 8);             // (N+1)*4
    int*  cursor  = row_ptr + (N_NODES + 1);                         // N*4
    int*  partials= cursor + N_NODES;                                // 2048*4
    const size_t need = 2 * embBytes + (size_t)NNZ * 8
                      + (size_t)(N_NODES + 1 + N_NODES + SCAN_BLOCKS) * 4;

    if (ws_size >= need) {
        // ---- CSR build (once; reused by all 3 layers) ----
        hipMemsetAsync(row_ptr, 0, (size_t)N_NODES * sizeof(int), stream);
        hist_rows<<<2048, 256, 0, stream>>>(rows, row_ptr);
        scan_block<<<SCAN_BLOCKS, 256, 0, stream>>>(row_ptr, partials);
        scan_partials<<<1, 256, 0, stream>>>(partials);
        add_offsets<<<SCAN_BLOCKS, 256, 0, stream>>>(row_ptr, cursor, partials);
        scatter_edges<<<2048, 256, 0, stream>>>(rows, cols, vals, cursor, sc);

        lgcn_init<<<4096, 256, 0, stream>>>((const float4*)ue, (const float4*)ie,
                                            (float4*)buf0, (float4*)acc);

        // ---- 3 atomic-free layers, acc update + final 1/4 fused ----
        float* cur = buf0;
        float* nxt = buf1;
        for (int l = 0; l < N_LAYERS; ++l) {
            const bool  last  = (l == N_LAYERS - 1);
            const float scale = last ? (1.0f / (N_LAYERS + 1)) : 1.0f;
            spmm_csr<<<N_NODES / 4, 256, 0, stream>>>(row_ptr, sc, cur, nxt, acc,
                                                      scale, last ? 0 : 1);
            float* t = cur; cur = nxt; nxt = t;
        }
    } else {
        // ---- fallback: round-1 proven path ----
        lgcn_init<<<4096, 256, 0, stream>>>((const float4*)ue, (const float4*)ie,
                                            (float4*)buf0, (float4*)acc);
        float* cur = buf0;
        float* nxt = buf1;
        for (int l = 0; l < N_LAYERS; ++l) {
            hipMemsetAsync(nxt, 0, embBytes, stream);
            lgcn_spmm_atomic<<<2048, 256, 0, stream>>>(rows, cols, vals, cur, nxt);
            const float scale = (l == N_LAYERS - 1) ? (1.0f / (N_LAYERS + 1)) : 1.0f;
            lgcn_add<<<4096, 256, 0, stream>>>((float4*)acc, (const float4*)nxt, scale);
            float* t = cur; cur = nxt; nxt = t;
        }
    }
}

// Round 3
// 713.861 us; speedup vs baseline: 1.5666x; 1.4728x over previous
//
#include <hip/hip_runtime.h>

// LightGCN propagation on MI355X — CSR, accumulator-free formulation.
// N = 524288 nodes, D = 64, NNZ = 1.25M, 3 layers, mean over 4 states.
// R2 lesson: fused acc RMW was 52% of SpMM traffic and the 2.4-edge row loop
// has no MLP. R3: layer k writes only e_k (no acc); layer1 gathers directly
// from ue/ie (no init copy); layer3 fuses the mean (ego+e1+e2+e3)/4; edge
// loop unrolled by 2 with independent partial sums.

constexpr int NUM_USER = 262144;
constexpr int NUM_ITEM = 262144;
constexpr int DIM      = 64;
constexpr int N_NODES  = NUM_USER + NUM_ITEM;   // 524288
constexpr int NNZ      = 1250000;
constexpr int N_LAYERS = 3;
constexpr int SCAN_BLOCKS = N_NODES / 256;      // 2048

// ---------------- CSR build ----------------
__global__ void hist_rows(const int* __restrict__ rows, int* __restrict__ counts) {
    int i = blockIdx.x * blockDim.x + threadIdx.x;
    const int stride = gridDim.x * blockDim.x;
    for (; i < NNZ; i += stride) atomicAdd(&counts[rows[i]], 1);
}

__global__ void scan_block(int* __restrict__ data, int* __restrict__ partials) {
    __shared__ int tmp[256];
    const int t = threadIdx.x;
    const int i = blockIdx.x * 256 + t;
    const int v = data[i];
    tmp[t] = v;
    __syncthreads();
    for (int off = 1; off < 256; off <<= 1) {
        int x = (t >= off) ? tmp[t - off] : 0;
        __syncthreads();
        tmp[t] += x;
        __syncthreads();
    }
    data[i] = tmp[t] - v;
    if (t == 255) partials[blockIdx.x] = tmp[255];
}

__global__ void scan_partials(int* __restrict__ p) {
    __shared__ int tmp[256];
    const int t = threadIdx.x;
    int loc[8];
    #pragma unroll
    for (int k = 0; k < 8; ++k) loc[k] = p[t * 8 + k];
    int run = 0;
    #pragma unroll
    for (int k = 0; k < 8; ++k) { int v = loc[k]; loc[k] = run; run += v; }
    tmp[t] = run;
    __syncthreads();
    for (int off = 1; off < 256; off <<= 1) {
        int x = (t >= off) ? tmp[t - off] : 0;
        __syncthreads();
        tmp[t] += x;
        __syncthreads();
    }
    const int excl = tmp[t] - run;
    #pragma unroll
    for (int k = 0; k < 8; ++k) p[t * 8 + k] = loc[k] + excl;
}

__global__ void add_offsets(int* __restrict__ rp, int* __restrict__ cursor,
                            const int* __restrict__ partials) {
    const int i = blockIdx.x * 256 + threadIdx.x;
    const int v = rp[i] + partials[blockIdx.x];
    rp[i] = v;
    cursor[i] = v;
    if (i == 0) rp[N_NODES] = NNZ;
}

__global__ void scatter_edges(const int* __restrict__ rows, const int* __restrict__ cols,
                              const float* __restrict__ vals, int* __restrict__ cursor,
                              int2* __restrict__ sc) {
    int i = blockIdx.x * blockDim.x + threadIdx.x;
    const int stride = gridDim.x * blockDim.x;
    for (; i < NNZ; i += stride) {
        const int pos = atomicAdd(&cursor[rows[i]], 1);
        sc[pos] = make_int2(cols[i], __float_as_int(vals[i]));
    }
}

// ---------------- SpMM layers (atomic-free, one wave per row) ----------------
__device__ __forceinline__ float ego_at(const float* __restrict__ ue,
                                        const float* __restrict__ ie,
                                        int node, int d) {
    return (node < NUM_USER) ? ue[((long)node << 6) + d]
                             : ie[((long)(node - NUM_USER) << 6) + d];
}

// e1 = A * ego  (gathers straight from inputs, uniform base select per edge)
__global__ void spmm_first(const int* __restrict__ ptr, const int2* __restrict__ sc,
                           const float* __restrict__ ue, const float* __restrict__ ie,
                           float* __restrict__ e1) {
    const int row = blockIdx.x * 4 + (threadIdx.x >> 6);
    const int d   = threadIdx.x & 63;
    const int beg = ptr[row];
    const int end = ptr[row + 1];
    float s0 = 0.f, s1 = 0.f;
    int e = beg;
    for (; e + 2 <= end; e += 2) {
        const int2 A = sc[e];
        const int2 B = sc[e + 1];
        s0 += __int_as_float(A.y) * ego_at(ue, ie, A.x, d);
        s1 += __int_as_float(B.y) * ego_at(ue, ie, B.x, d);
    }
    if (e < end) {
        const int2 A = sc[e];
        s0 += __int_as_float(A.y) * ego_at(ue, ie, A.x, d);
    }
    e1[((long)row << 6) + d] = s0 + s1;
}

// y = A * x
__global__ void spmm_mid(const int* __restrict__ ptr, const int2* __restrict__ sc,
                         const float* __restrict__ x, float* __restrict__ y) {
    const int row = blockIdx.x * 4 + (threadIdx.x >> 6);
    const int d   = threadIdx.x & 63;
    const int beg = ptr[row];
    const int end = ptr[row + 1];
    float s0 = 0.f, s1 = 0.f;
    int e = beg;
    for (; e + 2 <= end; e += 2) {
        const int2 A = sc[e];
        const int2 B = sc[e + 1];
        s0 += __int_as_float(A.y) * x[((long)A.x << 6) + d];
        s1 += __int_as_float(B.y) * x[((long)B.x << 6) + d];
    }
    if (e < end) {
        const int2 A = sc[e];
        s0 += __int_as_float(A.y) * x[((long)A.x << 6) + d];
    }
    y[((long)row << 6) + d] = s0 + s1;
}

// e3 = A * e2 in regs; out = (ego + e1 + e2 + e3) / 4
__global__ void spmm_last(const int* __restrict__ ptr, const int2* __restrict__ sc,
                          const float* __restrict__ ue, const float* __restrict__ ie,
                          const float* __restrict__ e1, const float* __restrict__ e2,
                          float* __restrict__ out) {
    const int row = blockIdx.x * 4 + (threadIdx.x >> 6);
    const int d   = threadIdx.x & 63;
    const int beg = ptr[row];
    const int end = ptr[row + 1];
    float s0 = 0.f, s1 = 0.f;
    int e = beg;
    for (; e + 2 <= end; e += 2) {
        const int2 A = sc[e];
        const int2 B = sc[e + 1];
        s0 += __int_as_float(A.y) * e2[((long)A.x << 6) + d];
        s1 += __int_as_float(B.y) * e2[((long)B.x << 6) + d];
    }
    if (e < end) {
        const int2 A = sc[e];
        s0 += __int_as_float(A.y) * e2[((long)A.x << 6) + d];
    }
    const long o = ((long)row << 6) + d;
    const float ego = (row < NUM_USER) ? ue[o] : ie[o - ((long)NUM_USER << 6)];
    out[o] = (ego + e1[o] + e2[o] + (s0 + s1)) * 0.25f;
}

// ---------------- fallback (round-1 proven path) ----------------
__global__ void lgcn_init(const float4* __restrict__ ue, const float4* __restrict__ ie,
                          float4* __restrict__ cur, float4* __restrict__ acc) {
    const long total  = (long)N_NODES * (DIM / 4);
    const long utotal = (long)NUM_USER * (DIM / 4);
    long i = (long)blockIdx.x * blockDim.x + threadIdx.x;
    const long stride = (long)gridDim.x * blockDim.x;
    for (; i < total; i += stride) {
        float4 v = (i < utotal) ? ue[i] : ie[i - utotal];
        cur[i] = v;
        acc[i] = v;
    }
}

__global__ void lgcn_spmm_atomic(const int* __restrict__ rows, const int* __restrict__ cols,
                                 const float* __restrict__ vals, const float* __restrict__ x,
                                 float* __restrict__ y) {
    const long total  = (long)NNZ * DIM;
    long t = (long)blockIdx.x * blockDim.x + threadIdx.x;
    const long stride = (long)gridDim.x * blockDim.x;
    for (; t < total; t += stride) {
        const int e = (int)(t >> 6);
        const int d = (int)(t & 63);
        atomicAdd(&y[((long)rows[e] << 6) + d], vals[e] * x[((long)cols[e] << 6) + d]);
    }
}

__global__ void lgcn_add(float4* __restrict__ acc, const float4* __restrict__ nxt, float scale) {
    const long total  = (long)N_NODES * (DIM / 4);
    long i = (long)blockIdx.x * blockDim.x + threadIdx.x;
    const long stride = (long)gridDim.x * blockDim.x;
    for (; i < total; i += stride) {
        float4 a = acc[i];
        const float4 b = nxt[i];
        a.x = (a.x + b.x) * scale;
        a.y = (a.y + b.y) * scale;
        a.z = (a.z + b.z) * scale;
        a.w = (a.w + b.w) * scale;
        acc[i] = a;
    }
}

extern "C" void kernel_launch(void* const* d_in, const int* in_sizes, int n_in,
                              void* d_out, int out_size, void* d_ws, size_t ws_size,
                              hipStream_t stream) {
    const float* ue   = (const float*)d_in[0];
    const float* ie   = (const float*)d_in[1];
    const int*   rows = (const int*)d_in[2];
    const int*   cols = (const int*)d_in[3];
    const float* vals = (const float*)d_in[4];
    float* out = (float*)d_out;

    const size_t embBytes = (size_t)N_NODES * DIM * sizeof(float);   // 134,217,728
    char* ws = (char*)d_ws;
    float* e1 = (float*)ws;                                          // 134 MB
    float* e2 = (float*)(ws + embBytes);                             // 134 MB
    int2* sc      = (int2*)(ws + 2 * embBytes);                      // 10 MB
    int*  row_ptr = (int*)((char*)sc + (size_t)NNZ * 8);             // (N+1)*4
    int*  cursor  = row_ptr + (N_NODES + 1);
    int*  partials= cursor + N_NODES;
    const size_t need = 2 * embBytes + (size_t)NNZ * 8
                      + (size_t)(N_NODES + 1 + N_NODES + SCAN_BLOCKS) * 4;

    if (ws_size >= need) {
        // ---- CSR build (once; reused by all 3 layers) ----
        hipMemsetAsync(row_ptr, 0, (size_t)N_NODES * sizeof(int), stream);
        hist_rows<<<2048, 256, 0, stream>>>(rows, row_ptr);
        scan_block<<<SCAN_BLOCKS, 256, 0, stream>>>(row_ptr, partials);
        scan_partials<<<1, 256, 0, stream>>>(partials);
        add_offsets<<<SCAN_BLOCKS, 256, 0, stream>>>(row_ptr, cursor, partials);
        scatter_edges<<<2048, 256, 0, stream>>>(rows, cols, vals, cursor, sc);

        // ---- 3 layers, no accumulator, mean fused into layer 3 ----
        spmm_first<<<N_NODES / 4, 256, 0, stream>>>(row_ptr, sc, ue, ie, e1);
        spmm_mid  <<<N_NODES / 4, 256, 0, stream>>>(row_ptr, sc, e1, e2);
        spmm_last <<<N_NODES / 4, 256, 0, stream>>>(row_ptr, sc, ue, ie, e1, e2, out);
    } else {
        // ---- fallback: round-1 proven path ----
        float* buf0 = e1;
        float* buf1 = e2;
        lgcn_init<<<4096, 256, 0, stream>>>((const float4*)ue, (const float4*)ie,
                                            (float4*)buf0, (float4*)out);
        float* cur = buf0;
        float* nxt = buf1;
        for (int l = 0; l < N_LAYERS; ++l) {
            hipMemsetAsync(nxt, 0, embBytes, stream);
            lgcn_spmm_atomic<<<2048, 256, 0, stream>>>(rows, cols, vals, cur, nxt);
            const float scale = (l == N_LAYERS - 1) ? (1.0f / (N_LAYERS + 1)) : 1.0f;
            lgcn_add<<<4096, 256, 0, stream>>>((float4*)out, (const float4*)nxt, scale);
            float* t = cur; cur = nxt; nxt = t;
        }
    }
}

// Round 4
// 465.857 us; speedup vs baseline: 2.4006x; 1.5324x over previous
//
#include <hip/hip_runtime.h>

// LightGCN propagation on MI355X — CSR + float4 (4 rows/wave) formulation.
// N = 524288 nodes, D = 64, NNZ = 1.25M, 3 layers, mean over 4 states.
// R3 lesson: byte count is near-minimal but achieved BW is only 2.2 TB/s —
// one wave per row (avg deg 2.4) leaves almost nothing in flight.
// R4: lane = float4 (4 dims), 16 lanes/row, 4 rows/wave -> 4 independent
// edge chains per wave (x2 unroll = up to 8 concurrent 256B gathers).

constexpr int NUM_USER = 262144;
constexpr int NUM_ITEM = 262144;
constexpr int DIM      = 64;
constexpr int N_NODES  = NUM_USER + NUM_ITEM;   // 524288
constexpr int NNZ      = 1250000;
constexpr int N_LAYERS = 3;
constexpr int SCAN_BLOCKS = N_NODES / 256;      // 2048
constexpr int ROWS_PER_BLOCK = 16;              // 256 threads / 16 lanes-per-row

// ---------------- CSR build ----------------
__global__ void hist_rows(const int* __restrict__ rows, int* __restrict__ counts) {
    int i = blockIdx.x * blockDim.x + threadIdx.x;
    const int stride = gridDim.x * blockDim.x;
    for (; i < NNZ; i += stride) atomicAdd(&counts[rows[i]], 1);
}

__global__ void scan_block(int* __restrict__ data, int* __restrict__ partials) {
    __shared__ int tmp[256];
    const int t = threadIdx.x;
    const int i = blockIdx.x * 256 + t;
    const int v = data[i];
    tmp[t] = v;
    __syncthreads();
    for (int off = 1; off < 256; off <<= 1) {
        int x = (t >= off) ? tmp[t - off] : 0;
        __syncthreads();
        tmp[t] += x;
        __syncthreads();
    }
    data[i] = tmp[t] - v;
    if (t == 255) partials[blockIdx.x] = tmp[255];
}

__global__ void scan_partials(int* __restrict__ p) {
    __shared__ int tmp[256];
    const int t = threadIdx.x;
    int loc[8];
    #pragma unroll
    for (int k = 0; k < 8; ++k) loc[k] = p[t * 8 + k];
    int run = 0;
    #pragma unroll
    for (int k = 0; k < 8; ++k) { int v = loc[k]; loc[k] = run; run += v; }
    tmp[t] = run;
    __syncthreads();
    for (int off = 1; off < 256; off <<= 1) {
        int x = (t >= off) ? tmp[t - off] : 0;
        __syncthreads();
        tmp[t] += x;
        __syncthreads();
    }
    const int excl = tmp[t] - run;
    #pragma unroll
    for (int k = 0; k < 8; ++k) p[t * 8 + k] = loc[k] + excl;
}

__global__ void add_offsets(int* __restrict__ rp, int* __restrict__ cursor,
                            const int* __restrict__ partials) {
    const int i = blockIdx.x * 256 + threadIdx.x;
    const int v = rp[i] + partials[blockIdx.x];
    rp[i] = v;
    cursor[i] = v;
    if (i == 0) rp[N_NODES] = NNZ;
}

__global__ void scatter_edges(const int* __restrict__ rows, const int* __restrict__ cols,
                              const float* __restrict__ vals, int* __restrict__ cursor,
                              int2* __restrict__ sc) {
    int i = blockIdx.x * blockDim.x + threadIdx.x;
    const int stride = gridDim.x * blockDim.x;
    for (; i < NNZ; i += stride) {
        const int pos = atomicAdd(&cursor[rows[i]], 1);
        sc[pos] = make_int2(cols[i], __float_as_int(vals[i]));
    }
}

// ---------------- float4 helpers ----------------
__device__ __forceinline__ void fma4(float4& s, float v, const float4 x) {
    s.x = fmaf(v, x.x, s.x);
    s.y = fmaf(v, x.y, s.y);
    s.z = fmaf(v, x.z, s.z);
    s.w = fmaf(v, x.w, s.w);
}

__device__ __forceinline__ float4 ego4_at(const float4* __restrict__ ue4,
                                          const float4* __restrict__ ie4,
                                          int node, int d4) {
    return (node < NUM_USER) ? ue4[node * 16 + d4]
                             : ie4[(node - NUM_USER) * 16 + d4];
}

// ---------------- SpMM layers: 16 lanes/row, 4 rows/wave ----------------
// e1 = A * ego
__global__ void spmm_first(const int* __restrict__ ptr, const int2* __restrict__ sc,
                           const float4* __restrict__ ue4, const float4* __restrict__ ie4,
                           float4* __restrict__ e1) {
    const int row = blockIdx.x * ROWS_PER_BLOCK + (threadIdx.x >> 4);
    const int d4  = threadIdx.x & 15;
    const int beg = ptr[row];
    const int end = ptr[row + 1];
    float4 s0 = {0.f, 0.f, 0.f, 0.f}, s1 = {0.f, 0.f, 0.f, 0.f};
    int e = beg;
    for (; e + 2 <= end; e += 2) {
        const int2 A = sc[e];
        const int2 B = sc[e + 1];
        fma4(s0, __int_as_float(A.y), ego4_at(ue4, ie4, A.x, d4));
        fma4(s1, __int_as_float(B.y), ego4_at(ue4, ie4, B.x, d4));
    }
    if (e < end) {
        const int2 A = sc[e];
        fma4(s0, __int_as_float(A.y), ego4_at(ue4, ie4, A.x, d4));
    }
    s0.x += s1.x; s0.y += s1.y; s0.z += s1.z; s0.w += s1.w;
    e1[row * 16 + d4] = s0;
}

// y = A * x
__global__ void spmm_mid(const int* __restrict__ ptr, const int2* __restrict__ sc,
                         const float4* __restrict__ x4, float4* __restrict__ y4) {
    const int row = blockIdx.x * ROWS_PER_BLOCK + (threadIdx.x >> 4);
    const int d4  = threadIdx.x & 15;
    const int beg = ptr[row];
    const int end = ptr[row + 1];
    float4 s0 = {0.f, 0.f, 0.f, 0.f}, s1 = {0.f, 0.f, 0.f, 0.f};
    int e = beg;
    for (; e + 2 <= end; e += 2) {
        const int2 A = sc[e];
        const int2 B = sc[e + 1];
        fma4(s0, __int_as_float(A.y), x4[A.x * 16 + d4]);
        fma4(s1, __int_as_float(B.y), x4[B.x * 16 + d4]);
    }
    if (e < end) {
        const int2 A = sc[e];
        fma4(s0, __int_as_float(A.y), x4[A.x * 16 + d4]);
    }
    s0.x += s1.x; s0.y += s1.y; s0.z += s1.z; s0.w += s1.w;
    y4[row * 16 + d4] = s0;
}

// e3 = A * e2 in regs; out = (ego + e1 + e2 + e3) / 4
__global__ void spmm_last(const int* __restrict__ ptr, const int2* __restrict__ sc,
                          const float4* __restrict__ ue4, const float4* __restrict__ ie4,
                          const float4* __restrict__ e1, const float4* __restrict__ e2,
                          float4* __restrict__ out4) {
    const int row = blockIdx.x * ROWS_PER_BLOCK + (threadIdx.x >> 4);
    const int d4  = threadIdx.x & 15;
    const int beg = ptr[row];
    const int end = ptr[row + 1];
    float4 s0 = {0.f, 0.f, 0.f, 0.f}, s1 = {0.f, 0.f, 0.f, 0.f};
    int e = beg;
    for (; e + 2 <= end; e += 2) {
        const int2 A = sc[e];
        const int2 B = sc[e + 1];
        fma4(s0, __int_as_float(A.y), e2[A.x * 16 + d4]);
        fma4(s1, __int_as_float(B.y), e2[B.x * 16 + d4]);
    }
    if (e < end) {
        const int2 A = sc[e];
        fma4(s0, __int_as_float(A.y), e2[A.x * 16 + d4]);
    }
    const int o = row * 16 + d4;
    const float4 g  = ego4_at(ue4, ie4, row, d4);
    const float4 a1 = e1[o];
    const float4 a2 = e2[o];
    float4 r;
    r.x = (g.x + a1.x + a2.x + s0.x + s1.x) * 0.25f;
    r.y = (g.y + a1.y + a2.y + s0.y + s1.y) * 0.25f;
    r.z = (g.z + a1.z + a2.z + s0.z + s1.z) * 0.25f;
    r.w = (g.w + a1.w + a2.w + s0.w + s1.w) * 0.25f;
    out4[o] = r;
}

// ---------------- fallback (round-1 proven path) ----------------
__global__ void lgcn_init(const float4* __restrict__ ue, const float4* __restrict__ ie,
                          float4* __restrict__ cur, float4* __restrict__ acc) {
    const long total  = (long)N_NODES * (DIM / 4);
    const long utotal = (long)NUM_USER * (DIM / 4);
    long i = (long)blockIdx.x * blockDim.x + threadIdx.x;
    const long stride = (long)gridDim.x * blockDim.x;
    for (; i < total; i += stride) {
        float4 v = (i < utotal) ? ue[i] : ie[i - utotal];
        cur[i] = v;
        acc[i] = v;
    }
}

__global__ void lgcn_spmm_atomic(const int* __restrict__ rows, const int* __restrict__ cols,
                                 const float* __restrict__ vals, const float* __restrict__ x,
                                 float* __restrict__ y) {
    const long total  = (long)NNZ * DIM;
    long t = (long)blockIdx.x * blockDim.x + threadIdx.x;
    const long stride = (long)gridDim.x * blockDim.x;
    for (; t < total; t += stride) {
        const int e = (int)(t >> 6);
        const int d = (int)(t & 63);
        atomicAdd(&y[((long)rows[e] << 6) + d], vals[e] * x[((long)cols[e] << 6) + d]);
    }
}

__global__ void lgcn_add(float4* __restrict__ acc, const float4* __restrict__ nxt, float scale) {
    const long total  = (long)N_NODES * (DIM / 4);
    long i = (long)blockIdx.x * blockDim.x + threadIdx.x;
    const long stride = (long)gridDim.x * blockDim.x;
    for (; i < total; i += stride) {
        float4 a = acc[i];
        const float4 b = nxt[i];
        a.x = (a.x + b.x) * scale;
        a.y = (a.y + b.y) * scale;
        a.z = (a.z + b.z) * scale;
        a.w = (a.w + b.w) * scale;
        acc[i] = a;
    }
}

extern "C" void kernel_launch(void* const* d_in, const int* in_sizes, int n_in,
                              void* d_out, int out_size, void* d_ws, size_t ws_size,
                              hipStream_t stream) {
    const float* ue   = (const float*)d_in[0];
    const float* ie   = (const float*)d_in[1];
    const int*   rows = (const int*)d_in[2];
    const int*   cols = (const int*)d_in[3];
    const float* vals = (const float*)d_in[4];
    float* out = (float*)d_out;

    const size_t embBytes = (size_t)N_NODES * DIM * sizeof(float);   // 134,217,728
    char* ws = (char*)d_ws;
    float* e1 = (float*)ws;                                          // 134 MB
    float* e2 = (float*)(ws + embBytes);                             // 134 MB
    int2* sc      = (int2*)(ws + 2 * embBytes);                      // 10 MB
    int*  row_ptr = (int*)((char*)sc + (size_t)NNZ * 8);             // (N+1)*4
    int*  cursor  = row_ptr + (N_NODES + 1);
    int*  partials= cursor + N_NODES;
    const size_t need = 2 * embBytes + (size_t)NNZ * 8
                      + (size_t)(N_NODES + 1 + N_NODES + SCAN_BLOCKS) * 4;

    if (ws_size >= need) {
        // ---- CSR build (once; reused by all 3 layers) ----
        hipMemsetAsync(row_ptr, 0, (size_t)N_NODES * sizeof(int), stream);
        hist_rows<<<2048, 256, 0, stream>>>(rows, row_ptr);
        scan_block<<<SCAN_BLOCKS, 256, 0, stream>>>(row_ptr, partials);
        scan_partials<<<1, 256, 0, stream>>>(partials);
        add_offsets<<<SCAN_BLOCKS, 256, 0, stream>>>(row_ptr, cursor, partials);
        scatter_edges<<<2048, 256, 0, stream>>>(rows, cols, vals, cursor, sc);

        // ---- 3 layers, no accumulator, mean fused into layer 3 ----
        const int grid = N_NODES / ROWS_PER_BLOCK;                   // 32768
        spmm_first<<<grid, 256, 0, stream>>>(row_ptr, sc,
                                             (const float4*)ue, (const float4*)ie,
                                             (float4*)e1);
        spmm_mid  <<<grid, 256, 0, stream>>>(row_ptr, sc,
                                             (const float4*)e1, (float4*)e2);
        spmm_last <<<grid, 256, 0, stream>>>(row_ptr, sc,
                                             (const float4*)ue, (const float4*)ie,
                                             (const float4*)e1, (const float4*)e2,
                                             (float4*)out);
    } else {
        // ---- fallback: round-1 proven path ----
        float* buf0 = e1;
        float* buf1 = e2;
        lgcn_init<<<4096, 256, 0, stream>>>((const float4*)ue, (const float4*)ie,
                                            (float4*)buf0, (float4*)out);
        float* cur = buf0;
        float* nxt = buf1;
        for (int l = 0; l < N_LAYERS; ++l) {
            hipMemsetAsync(nxt, 0, embBytes, stream);
            lgcn_spmm_atomic<<<2048, 256, 0, stream>>>(rows, cols, vals, cur, nxt);
            const float scale = (l == N_LAYERS - 1) ? (1.0f / (N_LAYERS + 1)) : 1.0f;
            lgcn_add<<<4096, 256, 0, stream>>>((float4*)out, (const float4*)nxt, scale);
            float* t = cur; cur = nxt; nxt = t;
        }
    }
}

// Round 5
// 371.415 us; speedup vs baseline: 3.0110x; 1.2543x over previous
//
#include <hip/hip_runtime.h>

// LightGCN propagation on MI355X — CSR + bf16-stored states (L3-resident gathers).
// N = 524288 nodes, D = 64, NNZ = 1.25M, 3 layers, mean over 4 states.
// R4 lesson: bytes near-minimal, BW 3.9 TB/s; gathers of 256B f32 rows from
// 134MB buffers miss L3. R5: store ego/e1/e2 as bf16 (67MB each, 128B rows)
// so all 3 gather targets (201MB) fit the 256MB Infinity Cache; compute stays
// f32; streams/writes on intermediates halve. Precision budget ~1.2e-5 vs
// 3.28e-5 threshold.

constexpr int NUM_USER = 262144;
constexpr int NUM_ITEM = 262144;
constexpr int DIM      = 64;
constexpr int N_NODES  = NUM_USER + NUM_ITEM;   // 524288
constexpr int NNZ      = 1250000;
constexpr int SCAN_BLOCKS = N_NODES / 256;      // 2048
constexpr int ROWS_PER_BLOCK = 16;              // 256 threads / 16 lanes-per-row

// ---------------- bf16 pack/unpack (RNE) ----------------
__device__ __forceinline__ unsigned bfpack2(float a, float b) {
    unsigned ua = __float_as_uint(a); ua += 0x7fffu + ((ua >> 16) & 1u);
    unsigned ub = __float_as_uint(b); ub += 0x7fffu + ((ub >> 16) & 1u);
    return (ua >> 16) | (ub & 0xffff0000u);
}
__device__ __forceinline__ uint2 bfpack4(float4 v) {
    return make_uint2(bfpack2(v.x, v.y), bfpack2(v.z, v.w));
}
__device__ __forceinline__ float4 bfunpack4(uint2 u) {
    float4 r;
    r.x = __uint_as_float(u.x << 16);
    r.y = __uint_as_float(u.x & 0xffff0000u);
    r.z = __uint_as_float(u.y << 16);
    r.w = __uint_as_float(u.y & 0xffff0000u);
    return r;
}
__device__ __forceinline__ void fma4(float4& s, float v, const float4 x) {
    s.x = fmaf(v, x.x, s.x);
    s.y = fmaf(v, x.y, s.y);
    s.z = fmaf(v, x.z, s.z);
    s.w = fmaf(v, x.w, s.w);
}

// ---------------- CSR build ----------------
__global__ void hist_rows(const int* __restrict__ rows, int* __restrict__ counts) {
    int i = blockIdx.x * blockDim.x + threadIdx.x;
    const int stride = gridDim.x * blockDim.x;
    for (; i < NNZ; i += stride) atomicAdd(&counts[rows[i]], 1);
}

__global__ void scan_block(int* __restrict__ data, int* __restrict__ partials) {
    __shared__ int tmp[256];
    const int t = threadIdx.x;
    const int i = blockIdx.x * 256 + t;
    const int v = data[i];
    tmp[t] = v;
    __syncthreads();
    for (int off = 1; off < 256; off <<= 1) {
        int x = (t >= off) ? tmp[t - off] : 0;
        __syncthreads();
        tmp[t] += x;
        __syncthreads();
    }
    data[i] = tmp[t] - v;
    if (t == 255) partials[blockIdx.x] = tmp[255];
}

__global__ void scan_partials(int* __restrict__ p) {
    __shared__ int tmp[256];
    const int t = threadIdx.x;
    int loc[8];
    #pragma unroll
    for (int k = 0; k < 8; ++k) loc[k] = p[t * 8 + k];
    int run = 0;
    #pragma unroll
    for (int k = 0; k < 8; ++k) { int v = loc[k]; loc[k] = run; run += v; }
    tmp[t] = run;
    __syncthreads();
    for (int off = 1; off < 256; off <<= 1) {
        int x = (t >= off) ? tmp[t - off] : 0;
        __syncthreads();
        tmp[t] += x;
        __syncthreads();
    }
    const int excl = tmp[t] - run;
    #pragma unroll
    for (int k = 0; k < 8; ++k) p[t * 8 + k] = loc[k] + excl;
}

__global__ void add_offsets(int* __restrict__ rp, int* __restrict__ cursor,
                            const int* __restrict__ partials) {
    const int i = blockIdx.x * 256 + threadIdx.x;
    const int v = rp[i] + partials[blockIdx.x];
    rp[i] = v;
    cursor[i] = v;
    if (i == 0) rp[N_NODES] = NNZ;
}

__global__ void scatter_edges(const int* __restrict__ rows, const int* __restrict__ cols,
                              const float* __restrict__ vals, int* __restrict__ cursor,
                              int2* __restrict__ sc) {
    int i = blockIdx.x * blockDim.x + threadIdx.x;
    const int stride = gridDim.x * blockDim.x;
    for (; i < NNZ; i += stride) {
        const int pos = atomicAdd(&cursor[rows[i]], 1);
        sc[pos] = make_int2(cols[i], __float_as_int(vals[i]));
    }
}

// ---------------- init: egob = bf16(concat(ue, ie)) ----------------
__global__ void init_egob(const float4* __restrict__ ue4, const float4* __restrict__ ie4,
                          uint2* __restrict__ egob) {
    const int total  = N_NODES * 16;
    const int utotal = NUM_USER * 16;
    int i = blockIdx.x * blockDim.x + threadIdx.x;
    const int stride = gridDim.x * blockDim.x;
    for (; i < total; i += stride) {
        float4 v = (i < utotal) ? ue4[i] : ie4[i - utotal];
        egob[i] = bfpack4(v);
    }
}

// ---------------- SpMM bf16->bf16: 16 lanes/row, 4 rows/wave ----------------
__global__ void spmm_b2b(const int* __restrict__ ptr, const int2* __restrict__ sc,
                         const uint2* __restrict__ xb, uint2* __restrict__ yb) {
    const int row = blockIdx.x * ROWS_PER_BLOCK + (threadIdx.x >> 4);
    const int d4  = threadIdx.x & 15;
    const int beg = ptr[row];
    const int end = ptr[row + 1];
    float4 s0 = {0.f, 0.f, 0.f, 0.f}, s1 = {0.f, 0.f, 0.f, 0.f};
    int e = beg;
    for (; e + 2 <= end; e += 2) {
        const int2 A = sc[e];
        const int2 B = sc[e + 1];
        const uint2 xa = xb[A.x * 16 + d4];
        const uint2 xc = xb[B.x * 16 + d4];
        fma4(s0, __int_as_float(A.y), bfunpack4(xa));
        fma4(s1, __int_as_float(B.y), bfunpack4(xc));
    }
    if (e < end) {
        const int2 A = sc[e];
        fma4(s0, __int_as_float(A.y), bfunpack4(xb[A.x * 16 + d4]));
    }
    s0.x += s1.x; s0.y += s1.y; s0.z += s1.z; s0.w += s1.w;
    yb[row * 16 + d4] = bfpack4(s0);
}

// ---------------- last layer: e3 in regs; out = (ego+e1+e2+e3)/4, f32 -------
__global__ void spmm_last(const int* __restrict__ ptr, const int2* __restrict__ sc,
                          const uint2* __restrict__ egob, const uint2* __restrict__ e1b,
                          const uint2* __restrict__ e2b, float4* __restrict__ out4) {
    const int row = blockIdx.x * ROWS_PER_BLOCK + (threadIdx.x >> 4);
    const int d4  = threadIdx.x & 15;
    const int beg = ptr[row];
    const int end = ptr[row + 1];
    float4 s0 = {0.f, 0.f, 0.f, 0.f}, s1 = {0.f, 0.f, 0.f, 0.f};
    int e = beg;
    for (; e + 2 <= end; e += 2) {
        const int2 A = sc[e];
        const int2 B = sc[e + 1];
        const uint2 xa = e2b[A.x * 16 + d4];
        const uint2 xc = e2b[B.x * 16 + d4];
        fma4(s0, __int_as_float(A.y), bfunpack4(xa));
        fma4(s1, __int_as_float(B.y), bfunpack4(xc));
    }
    if (e < end) {
        const int2 A = sc[e];
        fma4(s0, __int_as_float(A.y), bfunpack4(e2b[A.x * 16 + d4]));
    }
    const int o = row * 16 + d4;
    const float4 g  = bfunpack4(egob[o]);
    const float4 a1 = bfunpack4(e1b[o]);
    const float4 a2 = bfunpack4(e2b[o]);
    float4 r;
    r.x = (g.x + a1.x + a2.x + s0.x + s1.x) * 0.25f;
    r.y = (g.y + a1.y + a2.y + s0.y + s1.y) * 0.25f;
    r.z = (g.z + a1.z + a2.z + s0.z + s1.z) * 0.25f;
    r.w = (g.w + a1.w + a2.w + s0.w + s1.w) * 0.25f;
    out4[o] = r;
}

// ---------------- fallback (round-1 proven path) ----------------
__global__ void lgcn_init(const float4* __restrict__ ue, const float4* __restrict__ ie,
                          float4* __restrict__ cur, float4* __restrict__ acc) {
    const long total  = (long)N_NODES * (DIM / 4);
    const long utotal = (long)NUM_USER * (DIM / 4);
    long i = (long)blockIdx.x * blockDim.x + threadIdx.x;
    const long stride = (long)gridDim.x * blockDim.x;
    for (; i < total; i += stride) {
        float4 v = (i < utotal) ? ue[i] : ie[i - utotal];
        cur[i] = v;
        acc[i] = v;
    }
}

__global__ void lgcn_spmm_atomic(const int* __restrict__ rows, const int* __restrict__ cols,
                                 const float* __restrict__ vals, const float* __restrict__ x,
                                 float* __restrict__ y) {
    const long total  = (long)NNZ * DIM;
    long t = (long)blockIdx.x * blockDim.x + threadIdx.x;
    const long stride = (long)gridDim.x * blockDim.x;
    for (; t < total; t += stride) {
        const int e = (int)(t >> 6);
        const int d = (int)(t & 63);
        atomicAdd(&y[((long)rows[e] << 6) + d], vals[e] * x[((long)cols[e] << 6) + d]);
    }
}

__global__ void lgcn_add(float4* __restrict__ acc, const float4* __restrict__ nxt, float scale) {
    const long total  = (long)N_NODES * (DIM / 4);
    long i = (long)blockIdx.x * blockDim.x + threadIdx.x;
    const long stride = (long)gridDim.x * blockDim.x;
    for (; i < total; i += stride) {
        float4 a = acc[i];
        const float4 b = nxt[i];
        a.x = (a.x + b.x) * scale;
        a.y = (a.y + b.y) * scale;
        a.z = (a.z + b.z) * scale;
        a.w = (a.w + b.w) * scale;
        acc[i] = a;
    }
}

extern "C" void kernel_launch(void* const* d_in, const int* in_sizes, int n_in,
                              void* d_out, int out_size, void* d_ws, size_t ws_size,
                              hipStream_t stream) {
    const float* ue   = (const float*)d_in[0];
    const float* ie   = (const float*)d_in[1];
    const int*   rows = (const int*)d_in[2];
    const int*   cols = (const int*)d_in[3];
    const float* vals = (const float*)d_in[4];
    float* out = (float*)d_out;

    const size_t embBytes  = (size_t)N_NODES * DIM * sizeof(float);  // 134,217,728
    const size_t embBytesH = embBytes / 2;                           // 67,108,864
    char* ws = (char*)d_ws;
    uint2* egob = (uint2*)ws;                                        // 67 MB
    uint2* e1b  = (uint2*)(ws + embBytesH);                          // 67 MB
    uint2* e2b  = (uint2*)(ws + 2 * embBytesH);                      // 67 MB
    int2* sc      = (int2*)(ws + 3 * embBytesH);                     // 10 MB
    int*  row_ptr = (int*)((char*)sc + (size_t)NNZ * 8);             // (N+1)*4
    int*  cursor  = row_ptr + (N_NODES + 1);
    int*  partials= cursor + N_NODES;
    const size_t need = 3 * embBytesH + (size_t)NNZ * 8
                      + (size_t)(N_NODES + 1 + N_NODES + SCAN_BLOCKS) * 4;

    if (ws_size >= need) {
        // ---- CSR build (once; reused by all 3 layers) ----
        hipMemsetAsync(row_ptr, 0, (size_t)N_NODES * sizeof(int), stream);
        hist_rows<<<2048, 256, 0, stream>>>(rows, row_ptr);
        scan_block<<<SCAN_BLOCKS, 256, 0, stream>>>(row_ptr, partials);
        scan_partials<<<1, 256, 0, stream>>>(partials);
        add_offsets<<<SCAN_BLOCKS, 256, 0, stream>>>(row_ptr, cursor, partials);
        scatter_edges<<<2048, 256, 0, stream>>>(rows, cols, vals, cursor, sc);

        // ---- bf16 ego, then 3 layers; mean fused into layer 3 ----
        init_egob<<<4096, 256, 0, stream>>>((const float4*)ue, (const float4*)ie, egob);
        const int grid = N_NODES / ROWS_PER_BLOCK;                   // 32768
        spmm_b2b <<<grid, 256, 0, stream>>>(row_ptr, sc, egob, e1b);
        spmm_b2b <<<grid, 256, 0, stream>>>(row_ptr, sc, e1b, e2b);
        spmm_last<<<grid, 256, 0, stream>>>(row_ptr, sc, egob, e1b, e2b, (float4*)out);
    } else {
        // ---- fallback: round-1 proven path (needs 2*embBytes) ----
        float* buf0 = (float*)ws;
        float* buf1 = (float*)(ws + embBytes);
        lgcn_init<<<4096, 256, 0, stream>>>((const float4*)ue, (const float4*)ie,
                                            (float4*)buf0, (float4*)out);
        float* cur = buf0;
        float* nxt = buf1;
        for (int l = 0; l < 3; ++l) {
            hipMemsetAsync(nxt, 0, embBytes, stream);
            lgcn_spmm_atomic<<<2048, 256, 0, stream>>>(rows, cols, vals, cur, nxt);
            const float scale = (l == 2) ? 0.25f : 1.0f;
            lgcn_add<<<4096, 256, 0, stream>>>((float4*)out, (const float4*)nxt, scale);
            float* t = cur; cur = nxt; nxt = t;
        }
    }
}

// Round 6
// 368.131 us; speedup vs baseline: 3.0379x; 1.0089x over previous
//
#include <hip/hip_runtime.h>

// LightGCN propagation on MI355X — CSR + bf16 states + bucketed edge sort.
// R5 lesson: scatter_edges wrote 82MB HBM for a 10MB array (random 8B writes,
// 1 edge per 64B line per XCD -> zero write merging) at 0.8 TB/s = 100us.
// R6: two-pass bucket sort. Pass1 groups edges by row>>11 (256 buckets) with
// per-block LDS histograms + grouped writes; pass2 permutes each ~4.9K-edge
// bucket entirely in LDS and streams it out coalesced. Bucket bases come free
// from row_ptr[b*2048]; no global cursor array at all.

constexpr int NUM_USER = 262144;
constexpr int NUM_ITEM = 262144;
constexpr int DIM      = 64;
constexpr int N_NODES  = NUM_USER + NUM_ITEM;   // 524288
constexpr int NNZ      = 1250000;
constexpr int SCAN_BLOCKS = N_NODES / 256;      // 2048
constexpr int ROWS_PER_BLOCK = 16;              // spmm: 16 lanes/row, 4 rows/wave

constexpr int NBUCK = 256;                      // bucket = row >> 11
constexpr int ROWS_PER_BUCK = N_NODES / NBUCK;  // 2048
constexpr int PB_BLOCKS = 512;
constexpr int CHUNK = (NNZ + PB_BLOCKS - 1) / PB_BLOCKS;  // 2442
constexpr int BCAP = 6144;                      // bucket mean 4883, sd ~70; 18 sigma

// ---------------- bf16 pack/unpack (RNE) ----------------
__device__ __forceinline__ unsigned bfpack2(float a, float b) {
    unsigned ua = __float_as_uint(a); ua += 0x7fffu + ((ua >> 16) & 1u);
    unsigned ub = __float_as_uint(b); ub += 0x7fffu + ((ub >> 16) & 1u);
    return (ua >> 16) | (ub & 0xffff0000u);
}
__device__ __forceinline__ uint2 bfpack4(float4 v) {
    return make_uint2(bfpack2(v.x, v.y), bfpack2(v.z, v.w));
}
__device__ __forceinline__ float4 bfunpack4(uint2 u) {
    float4 r;
    r.x = __uint_as_float(u.x << 16);
    r.y = __uint_as_float(u.x & 0xffff0000u);
    r.z = __uint_as_float(u.y << 16);
    r.w = __uint_as_float(u.y & 0xffff0000u);
    return r;
}
__device__ __forceinline__ void fma4(float4& s, float v, const float4 x) {
    s.x = fmaf(v, x.x, s.x);
    s.y = fmaf(v, x.y, s.y);
    s.z = fmaf(v, x.z, s.z);
    s.w = fmaf(v, x.w, s.w);
}

// ---------------- CSR row_ptr build ----------------
__global__ void hist_rows(const int* __restrict__ rows, int* __restrict__ counts) {
    int i = blockIdx.x * blockDim.x + threadIdx.x;
    const int stride = gridDim.x * blockDim.x;
    for (; i < NNZ; i += stride) atomicAdd(&counts[rows[i]], 1);
}

__global__ void scan_block(int* __restrict__ data, int* __restrict__ partials) {
    __shared__ int tmp[256];
    const int t = threadIdx.x;
    const int i = blockIdx.x * 256 + t;
    const int v = data[i];
    tmp[t] = v;
    __syncthreads();
    for (int off = 1; off < 256; off <<= 1) {
        int x = (t >= off) ? tmp[t - off] : 0;
        __syncthreads();
        tmp[t] += x;
        __syncthreads();
    }
    data[i] = tmp[t] - v;
    if (t == 255) partials[blockIdx.x] = tmp[255];
}

__global__ void scan_partials(int* __restrict__ p) {
    __shared__ int tmp[256];
    const int t = threadIdx.x;
    int loc[8];
    #pragma unroll
    for (int k = 0; k < 8; ++k) loc[k] = p[t * 8 + k];
    int run = 0;
    #pragma unroll
    for (int k = 0; k < 8; ++k) { int v = loc[k]; loc[k] = run; run += v; }
    tmp[t] = run;
    __syncthreads();
    for (int off = 1; off < 256; off <<= 1) {
        int x = (t >= off) ? tmp[t - off] : 0;
        __syncthreads();
        tmp[t] += x;
        __syncthreads();
    }
    const int excl = tmp[t] - run;
    #pragma unroll
    for (int k = 0; k < 8; ++k) p[t * 8 + k] = loc[k] + excl;
}

// row_ptr finalize + free bucket cursors (bucket base = row_ptr[b*2048])
__global__ void add_offsets(int* __restrict__ rp, int* __restrict__ bcur,
                            const int* __restrict__ partials) {
    const int i = blockIdx.x * 256 + threadIdx.x;
    const int v = rp[i] + partials[blockIdx.x];
    rp[i] = v;
    if ((i & (ROWS_PER_BUCK - 1)) == 0) bcur[i / ROWS_PER_BUCK] = v;
    if (i == 0) rp[N_NODES] = NNZ;
}

// ---------------- bucketed edge sort ----------------
// pass1: group edges by bucket with per-block LDS histogram + grouped writes
__global__ void bucket_pass1(const int* __restrict__ rows, const int* __restrict__ cols,
                             const float* __restrict__ vals, int* __restrict__ bcur,
                             int2* __restrict__ eb, unsigned short* __restrict__ ebrow) {
    __shared__ int lcnt[NBUCK];
    __shared__ int lbase[NBUCK];
    __shared__ int lofs[NBUCK];
    const int t   = threadIdx.x;
    const int beg = blockIdx.x * CHUNK;
    const int end = min(beg + CHUNK, NNZ);
    lcnt[t] = 0;
    __syncthreads();
    for (int i = beg + t; i < end; i += 256)
        atomicAdd(&lcnt[rows[i] >> 11], 1);
    __syncthreads();
    lofs[t]  = 0;
    lbase[t] = lcnt[t] ? atomicAdd(&bcur[t], lcnt[t]) : 0;
    __syncthreads();
    for (int i = beg + t; i < end; i += 256) {
        const int r = rows[i];
        const int b = r >> 11;
        const int p = lbase[b] + atomicAdd(&lofs[b], 1);
        eb[p]    = make_int2(cols[i], __float_as_int(vals[i]));
        ebrow[p] = (unsigned short)(r & (ROWS_PER_BUCK - 1));
    }
}

// pass2: one block per bucket; permute in LDS, stream out coalesced
__global__ void bucket_pass2(const int* __restrict__ row_ptr,
                             const int2* __restrict__ eb,
                             const unsigned short* __restrict__ ebrow,
                             int2* __restrict__ sc) {
    __shared__ int  lcur[ROWS_PER_BUCK];
    __shared__ int2 lout[BCAP];
    const int b    = blockIdx.x;
    const int t    = threadIdx.x;
    const int base = row_ptr[b * ROWS_PER_BUCK];
    const int cnt  = row_ptr[(b + 1) * ROWS_PER_BUCK] - base;  // rp[N]=NNZ for b=255
    for (int r = t; r < ROWS_PER_BUCK; r += 256)
        lcur[r] = row_ptr[b * ROWS_PER_BUCK + r] - base;
    __syncthreads();
    if (cnt <= BCAP) {
        for (int i = t; i < cnt; i += 256) {
            const int rl = ebrow[base + i];
            const int p  = atomicAdd(&lcur[rl], 1);
            lout[p] = eb[base + i];
        }
        __syncthreads();
        for (int i = t; i < cnt; i += 256)
            sc[base + i] = lout[i];
    } else {  // statistically impossible; correctness guard
        for (int i = t; i < cnt; i += 256) {
            const int rl = ebrow[base + i];
            const int p  = atomicAdd(&lcur[rl], 1);
            sc[base + p] = eb[base + i];
        }
    }
}

// ---------------- init: egob = bf16(concat(ue, ie)) ----------------
__global__ void init_egob(const float4* __restrict__ ue4, const float4* __restrict__ ie4,
                          uint2* __restrict__ egob) {
    const int total  = N_NODES * 16;
    const int utotal = NUM_USER * 16;
    int i = blockIdx.x * blockDim.x + threadIdx.x;
    const int stride = gridDim.x * blockDim.x;
    for (; i < total; i += stride) {
        float4 v = (i < utotal) ? ue4[i] : ie4[i - utotal];
        egob[i] = bfpack4(v);
    }
}

// ---------------- SpMM bf16->bf16: 16 lanes/row, 4 rows/wave ----------------
__global__ void spmm_b2b(const int* __restrict__ ptr, const int2* __restrict__ sc,
                         const uint2* __restrict__ xb, uint2* __restrict__ yb) {
    const int row = blockIdx.x * ROWS_PER_BLOCK + (threadIdx.x >> 4);
    const int d4  = threadIdx.x & 15;
    const int beg = ptr[row];
    const int end = ptr[row + 1];
    float4 s0 = {0.f, 0.f, 0.f, 0.f}, s1 = {0.f, 0.f, 0.f, 0.f};
    int e = beg;
    for (; e + 2 <= end; e += 2) {
        const int2 A = sc[e];
        const int2 B = sc[e + 1];
        const uint2 xa = xb[A.x * 16 + d4];
        const uint2 xc = xb[B.x * 16 + d4];
        fma4(s0, __int_as_float(A.y), bfunpack4(xa));
        fma4(s1, __int_as_float(B.y), bfunpack4(xc));
    }
    if (e < end) {
        const int2 A = sc[e];
        fma4(s0, __int_as_float(A.y), bfunpack4(xb[A.x * 16 + d4]));
    }
    s0.x += s1.x; s0.y += s1.y; s0.z += s1.z; s0.w += s1.w;
    yb[row * 16 + d4] = bfpack4(s0);
}

// ---------------- last layer: e3 in regs; out = (ego+e1+e2+e3)/4, f32 -------
__global__ void spmm_last(const int* __restrict__ ptr, const int2* __restrict__ sc,
                          const uint2* __restrict__ egob, const uint2* __restrict__ e1b,
                          const uint2* __restrict__ e2b, float4* __restrict__ out4) {
    const int row = blockIdx.x * ROWS_PER_BLOCK + (threadIdx.x >> 4);
    const int d4  = threadIdx.x & 15;
    const int beg = ptr[row];
    const int end = ptr[row + 1];
    float4 s0 = {0.f, 0.f, 0.f, 0.f}, s1 = {0.f, 0.f, 0.f, 0.f};
    int e = beg;
    for (; e + 2 <= end; e += 2) {
        const int2 A = sc[e];
        const int2 B = sc[e + 1];
        const uint2 xa = e2b[A.x * 16 + d4];
        const uint2 xc = e2b[B.x * 16 + d4];
        fma4(s0, __int_as_float(A.y), bfunpack4(xa));
        fma4(s1, __int_as_float(B.y), bfunpack4(xc));
    }
    if (e < end) {
        const int2 A = sc[e];
        fma4(s0, __int_as_float(A.y), bfunpack4(e2b[A.x * 16 + d4]));
    }
    const int o = row * 16 + d4;
    const float4 g  = bfunpack4(egob[o]);
    const float4 a1 = bfunpack4(e1b[o]);
    const float4 a2 = bfunpack4(e2b[o]);
    float4 r;
    r.x = (g.x + a1.x + a2.x + s0.x + s1.x) * 0.25f;
    r.y = (g.y + a1.y + a2.y + s0.y + s1.y) * 0.25f;
    r.z = (g.z + a1.z + a2.z + s0.z + s1.z) * 0.25f;
    r.w = (g.w + a1.w + a2.w + s0.w + s1.w) * 0.25f;
    out4[o] = r;
}

// ---------------- fallback (round-1 proven path) ----------------
__global__ void lgcn_init(const float4* __restrict__ ue, const float4* __restrict__ ie,
                          float4* __restrict__ cur, float4* __restrict__ acc) {
    const long total  = (long)N_NODES * (DIM / 4);
    const long utotal = (long)NUM_USER * (DIM / 4);
    long i = (long)blockIdx.x * blockDim.x + threadIdx.x;
    const long stride = (long)gridDim.x * blockDim.x;
    for (; i < total; i += stride) {
        float4 v = (i < utotal) ? ue[i] : ie[i - utotal];
        cur[i] = v;
        acc[i] = v;
    }
}

__global__ void lgcn_spmm_atomic(const int* __restrict__ rows, const int* __restrict__ cols,
                                 const float* __restrict__ vals, const float* __restrict__ x,
                                 float* __restrict__ y) {
    const long total  = (long)NNZ * DIM;
    long t = (long)blockIdx.x * blockDim.x + threadIdx.x;
    const long stride = (long)gridDim.x * blockDim.x;
    for (; t < total; t += stride) {
        const int e = (int)(t >> 6);
        const int d = (int)(t & 63);
        atomicAdd(&y[((long)rows[e] << 6) + d], vals[e] * x[((long)cols[e] << 6) + d]);
    }
}

__global__ void lgcn_add(float4* __restrict__ acc, const float4* __restrict__ nxt, float scale) {
    const long total  = (long)N_NODES * (DIM / 4);
    long i = (long)blockIdx.x * blockDim.x + threadIdx.x;
    const long stride = (long)gridDim.x * blockDim.x;
    for (; i < total; i += stride) {
        float4 a = acc[i];
        const float4 b = nxt[i];
        a.x = (a.x + b.x) * scale;
        a.y = (a.y + b.y) * scale;
        a.z = (a.z + b.z) * scale;
        a.w = (a.w + b.w) * scale;
        acc[i] = a;
    }
}

extern "C" void kernel_launch(void* const* d_in, const int* in_sizes, int n_in,
                              void* d_out, int out_size, void* d_ws, size_t ws_size,
                              hipStream_t stream) {
    const float* ue   = (const float*)d_in[0];
    const float* ie   = (const float*)d_in[1];
    const int*   rows = (const int*)d_in[2];
    const int*   cols = (const int*)d_in[3];
    const float* vals = (const float*)d_in[4];
    float* out = (float*)d_out;

    const size_t embBytes  = (size_t)N_NODES * DIM * sizeof(float);  // 134,217,728
    const size_t embBytesH = embBytes / 2;                           // 67,108,864
    char* ws = (char*)d_ws;
    uint2* egob = (uint2*)ws;                                        // 67 MB
    uint2* e1b  = (uint2*)(ws + embBytesH);                          // 67 MB
    uint2* e2b  = (uint2*)(ws + 2 * embBytesH);                      // 67 MB
    char* p = ws + 3 * embBytesH;
    int2* sc = (int2*)p;                 p += (size_t)NNZ * 8;       // 10 MB
    int2* eb = (int2*)p;                 p += (size_t)NNZ * 8;       // 10 MB
    unsigned short* ebrow = (unsigned short*)p; p += (size_t)NNZ * 2;// 2.5 MB
    int* row_ptr  = (int*)p;             p += (size_t)(N_NODES + 1) * 4;
    int* partials = (int*)p;             p += (size_t)SCAN_BLOCKS * 4;
    int* bcur     = (int*)p;             p += (size_t)NBUCK * 4;
    const size_t need = (size_t)(p - ws);

    if (ws_size >= need) {
        // ---- row_ptr build ----
        hipMemsetAsync(row_ptr, 0, (size_t)N_NODES * sizeof(int), stream);
        hist_rows<<<2048, 256, 0, stream>>>(rows, row_ptr);
        scan_block<<<SCAN_BLOCKS, 256, 0, stream>>>(row_ptr, partials);
        scan_partials<<<1, 256, 0, stream>>>(partials);
        add_offsets<<<SCAN_BLOCKS, 256, 0, stream>>>(row_ptr, bcur, partials);
        // ---- bucketed edge sort -> sc ----
        bucket_pass1<<<PB_BLOCKS, 256, 0, stream>>>(rows, cols, vals, bcur, eb, ebrow);
        bucket_pass2<<<NBUCK, 256, 0, stream>>>(row_ptr, eb, ebrow, sc);

        // ---- bf16 ego, then 3 layers; mean fused into layer 3 ----
        init_egob<<<4096, 256, 0, stream>>>((const float4*)ue, (const float4*)ie, egob);
        const int grid = N_NODES / ROWS_PER_BLOCK;                   // 32768
        spmm_b2b <<<grid, 256, 0, stream>>>(row_ptr, sc, egob, e1b);
        spmm_b2b <<<grid, 256, 0, stream>>>(row_ptr, sc, e1b, e2b);
        spmm_last<<<grid, 256, 0, stream>>>(row_ptr, sc, egob, e1b, e2b, (float4*)out);
    } else {
        // ---- fallback: round-1 proven path (needs 2*embBytes) ----
        float* buf0 = (float*)ws;
        float* buf1 = (float*)(ws + embBytes);
        lgcn_init<<<4096, 256, 0, stream>>>((const float4*)ue, (const float4*)ie,
                                            (float4*)buf0, (float4*)out);
        float* cur = buf0;
        float* nxt = buf1;
        for (int l = 0; l < 3; ++l) {
            hipMemsetAsync(nxt, 0, embBytes, stream);
            lgcn_spmm_atomic<<<2048, 256, 0, stream>>>(rows, cols, vals, cur, nxt);
            const float scale = (l == 2) ? 0.25f : 1.0f;
            lgcn_add<<<4096, 256, 0, stream>>>((float4*)out, (const float4*)nxt, scale);
            float* t = cur; cur = nxt; nxt = t;
        }
    }
}

// Round 7
// 310.089 us; speedup vs baseline: 3.6065x; 1.1872x over previous
//
#include <hip/hip_runtime.h>

// LightGCN propagation on MI355X — bf16 states + histogram-free bucketed CSR.
// R6 lesson: ~150us hid in preprocessing (hist_rows = 1.25M random atomics
// over 2MB -> 64B-line RMW, + 3 global scan passes). R7: deterministic bucket
// pipeline (count -> scan-over-blocks -> bucket-base scan -> offset scatter ->
// per-bucket LDS finalize building row_ptr AND sorted sc), ~65MB total traffic.
// Also drop egob/init (201MB): layer1 gathers f32 from ue/ie (134MB, L3-fits),
// last-layer epilogue streams ue/ie f32.

constexpr int NUM_USER = 262144;
constexpr int NUM_ITEM = 262144;
constexpr int DIM      = 64;
constexpr int N_NODES  = NUM_USER + NUM_ITEM;   // 524288
constexpr int NNZ      = 1250000;
constexpr int ROWS_PER_BLOCK = 16;              // spmm: 16 lanes/row, 4 rows/wave

constexpr int NBUCK = 256;                      // bucket = row >> 11
constexpr int ROWS_PER_BUCK = N_NODES / NBUCK;  // 2048
constexpr int PB_BLOCKS = 512;
constexpr int CHUNK = (NNZ + PB_BLOCKS - 1) / PB_BLOCKS;  // 2442
constexpr int BCAP = 6144;                      // bucket mean 4883, sd ~70

// ---------------- bf16 pack/unpack (RNE) ----------------
__device__ __forceinline__ unsigned bfpack2(float a, float b) {
    unsigned ua = __float_as_uint(a); ua += 0x7fffu + ((ua >> 16) & 1u);
    unsigned ub = __float_as_uint(b); ub += 0x7fffu + ((ub >> 16) & 1u);
    return (ua >> 16) | (ub & 0xffff0000u);
}
__device__ __forceinline__ uint2 bfpack4(float4 v) {
    return make_uint2(bfpack2(v.x, v.y), bfpack2(v.z, v.w));
}
__device__ __forceinline__ float4 bfunpack4(uint2 u) {
    float4 r;
    r.x = __uint_as_float(u.x << 16);
    r.y = __uint_as_float(u.x & 0xffff0000u);
    r.z = __uint_as_float(u.y << 16);
    r.w = __uint_as_float(u.y & 0xffff0000u);
    return r;
}
__device__ __forceinline__ void fma4(float4& s, float v, const float4 x) {
    s.x = fmaf(v, x.x, s.x);
    s.y = fmaf(v, x.y, s.y);
    s.z = fmaf(v, x.z, s.z);
    s.w = fmaf(v, x.w, s.w);
}
__device__ __forceinline__ float4 ego4_at(const float4* __restrict__ ue4,
                                          const float4* __restrict__ ie4,
                                          int node, int d4) {
    return (node < NUM_USER) ? ue4[node * 16 + d4]
                             : ie4[(node - NUM_USER) * 16 + d4];
}

// ---------------- bucket pipeline ----------------
// k1: per-block bucket histogram (LDS only; writes 256 ints/block)
__global__ void bucket_count(const int* __restrict__ rows, int* __restrict__ bcnt) {
    __shared__ int lcnt[NBUCK];
    const int t = threadIdx.x;
    lcnt[t] = 0;
    __syncthreads();
    const int beg = blockIdx.x * CHUNK;
    const int end = min(beg + CHUNK, NNZ);
    for (int i = beg + t; i < end; i += 256)
        atomicAdd(&lcnt[rows[i] >> 11], 1);
    __syncthreads();
    bcnt[t * PB_BLOCKS + blockIdx.x] = lcnt[t];
}

// k2a: per bucket, exclusive scan over the 512 block counts (in place)
__global__ void scan_bcnt(int* __restrict__ bcnt, int* __restrict__ tot) {
    __shared__ int tmp[256];
    const int b = blockIdx.x, t = threadIdx.x;
    const int a0 = bcnt[b * PB_BLOCKS + 2 * t];
    const int a1 = bcnt[b * PB_BLOCKS + 2 * t + 1];
    const int run = a0 + a1;
    tmp[t] = run;
    __syncthreads();
    for (int off = 1; off < 256; off <<= 1) {
        int x = (t >= off) ? tmp[t - off] : 0;
        __syncthreads();
        tmp[t] += x;
        __syncthreads();
    }
    const int excl = tmp[t] - run;
    bcnt[b * PB_BLOCKS + 2 * t]     = excl;
    bcnt[b * PB_BLOCKS + 2 * t + 1] = excl + a0;
    if (t == 255) tot[b] = tmp[255];
}

// k2b: exclusive scan of the 256 bucket totals -> bbase[257]
__global__ void scan_btot(const int* __restrict__ tot, int* __restrict__ bbase) {
    __shared__ int tmp[256];
    const int t = threadIdx.x;
    const int v = tot[t];
    tmp[t] = v;
    __syncthreads();
    for (int off = 1; off < 256; off <<= 1) {
        int x = (t >= off) ? tmp[t - off] : 0;
        __syncthreads();
        tmp[t] += x;
        __syncthreads();
    }
    bbase[t] = tmp[t] - v;
    if (t == 0) bbase[NBUCK] = NNZ;
}

// k3: grouped scatter using precomputed offsets (no global atomics)
__global__ void bucket_scatter(const int* __restrict__ rows, const int* __restrict__ cols,
                               const float* __restrict__ vals,
                               const int* __restrict__ bcnt, const int* __restrict__ bbase,
                               int2* __restrict__ eb, unsigned short* __restrict__ ebrow) {
    __shared__ int lbase[NBUCK];
    __shared__ int lofs[NBUCK];
    const int t = threadIdx.x;
    lbase[t] = bbase[t] + bcnt[t * PB_BLOCKS + blockIdx.x];
    lofs[t] = 0;
    __syncthreads();
    const int beg = blockIdx.x * CHUNK;
    const int end = min(beg + CHUNK, NNZ);
    for (int i = beg + t; i < end; i += 256) {
        const int r = rows[i];
        const int b = r >> 11;
        const int p = lbase[b] + atomicAdd(&lofs[b], 1);
        eb[p]    = make_int2(cols[i], __float_as_int(vals[i]));
        ebrow[p] = (unsigned short)(r & (ROWS_PER_BUCK - 1));
    }
}

// k4: per bucket — row histogram, 2048-scan, row_ptr write, LDS permute -> sc
__global__ void bucket_finalize(const int* __restrict__ bbase,
                                const int2* __restrict__ eb,
                                const unsigned short* __restrict__ ebrow,
                                int* __restrict__ row_ptr, int2* __restrict__ sc) {
    __shared__ int  lcnt[ROWS_PER_BUCK];   // 8 KB: counts -> excl scan -> cursors
    __shared__ int  tmp[256];              // 1 KB
    __shared__ int2 lout[BCAP];            // 48 KB
    const int b    = blockIdx.x;
    const int t    = threadIdx.x;
    const int base = bbase[b];
    const int cnt  = bbase[b + 1] - base;
    for (int r = t; r < ROWS_PER_BUCK; r += 256) lcnt[r] = 0;
    __syncthreads();
    for (int i = t; i < cnt; i += 256)
        atomicAdd(&lcnt[ebrow[base + i]], 1);
    __syncthreads();
    // exclusive scan of 2048 in place (8 per thread)
    int loc[8];
    int run = 0;
    #pragma unroll
    for (int k = 0; k < 8; ++k) { const int v = lcnt[t * 8 + k]; loc[k] = run; run += v; }
    tmp[t] = run;
    __syncthreads();
    for (int off = 1; off < 256; off <<= 1) {
        int x = (t >= off) ? tmp[t - off] : 0;
        __syncthreads();
        tmp[t] += x;
        __syncthreads();
    }
    const int excl = tmp[t] - run;
    #pragma unroll
    for (int k = 0; k < 8; ++k) lcnt[t * 8 + k] = loc[k] + excl;
    __syncthreads();
    // row_ptr (coalesced)
    for (int r = t; r < ROWS_PER_BUCK; r += 256)
        row_ptr[b * ROWS_PER_BUCK + r] = base + lcnt[r];
    if (b == NBUCK - 1 && t == 0) row_ptr[N_NODES] = NNZ;
    __syncthreads();
    // permute: lcnt now serves as in-bucket cursors
    if (cnt <= BCAP) {
        for (int i = t; i < cnt; i += 256) {
            const int p = atomicAdd(&lcnt[ebrow[base + i]], 1);
            lout[p] = eb[base + i];
        }
        __syncthreads();
        for (int i = t; i < cnt; i += 256)
            sc[base + i] = lout[i];
    } else {  // statistically impossible; correctness guard
        for (int i = t; i < cnt; i += 256) {
            const int p = atomicAdd(&lcnt[ebrow[base + i]], 1);
            sc[base + p] = eb[base + i];
        }
    }
}

// ---------------- SpMM layers: 16 lanes/row, 4 rows/wave ----------------
// layer 1: gather f32 straight from ue/ie, write bf16 e1
__global__ void spmm_first(const int* __restrict__ ptr, const int2* __restrict__ sc,
                           const float4* __restrict__ ue4, const float4* __restrict__ ie4,
                           uint2* __restrict__ e1b) {
    const int row = blockIdx.x * ROWS_PER_BLOCK + (threadIdx.x >> 4);
    const int d4  = threadIdx.x & 15;
    const int beg = ptr[row];
    const int end = ptr[row + 1];
    float4 s0 = {0.f, 0.f, 0.f, 0.f}, s1 = {0.f, 0.f, 0.f, 0.f};
    int e = beg;
    for (; e + 2 <= end; e += 2) {
        const int2 A = sc[e];
        const int2 B = sc[e + 1];
        fma4(s0, __int_as_float(A.y), ego4_at(ue4, ie4, A.x, d4));
        fma4(s1, __int_as_float(B.y), ego4_at(ue4, ie4, B.x, d4));
    }
    if (e < end) {
        const int2 A = sc[e];
        fma4(s0, __int_as_float(A.y), ego4_at(ue4, ie4, A.x, d4));
    }
    s0.x += s1.x; s0.y += s1.y; s0.z += s1.z; s0.w += s1.w;
    e1b[row * 16 + d4] = bfpack4(s0);
}

// layer 2: bf16 -> bf16
__global__ void spmm_b2b(const int* __restrict__ ptr, const int2* __restrict__ sc,
                         const uint2* __restrict__ xb, uint2* __restrict__ yb) {
    const int row = blockIdx.x * ROWS_PER_BLOCK + (threadIdx.x >> 4);
    const int d4  = threadIdx.x & 15;
    const int beg = ptr[row];
    const int end = ptr[row + 1];
    float4 s0 = {0.f, 0.f, 0.f, 0.f}, s1 = {0.f, 0.f, 0.f, 0.f};
    int e = beg;
    for (; e + 2 <= end; e += 2) {
        const int2 A = sc[e];
        const int2 B = sc[e + 1];
        const uint2 xa = xb[A.x * 16 + d4];
        const uint2 xc = xb[B.x * 16 + d4];
        fma4(s0, __int_as_float(A.y), bfunpack4(xa));
        fma4(s1, __int_as_float(B.y), bfunpack4(xc));
    }
    if (e < end) {
        const int2 A = sc[e];
        fma4(s0, __int_as_float(A.y), bfunpack4(xb[A.x * 16 + d4]));
    }
    s0.x += s1.x; s0.y += s1.y; s0.z += s1.z; s0.w += s1.w;
    yb[row * 16 + d4] = bfpack4(s0);
}

// layer 3: e3 in regs; out = (ego_f32 + e1 + e2 + e3) / 4
__global__ void spmm_last(const int* __restrict__ ptr, const int2* __restrict__ sc,
                          const float4* __restrict__ ue4, const float4* __restrict__ ie4,
                          const uint2* __restrict__ e1b, const uint2* __restrict__ e2b,
                          float4* __restrict__ out4) {
    const int row = blockIdx.x * ROWS_PER_BLOCK + (threadIdx.x >> 4);
    const int d4  = threadIdx.x & 15;
    const int beg = ptr[row];
    const int end = ptr[row + 1];
    float4 s0 = {0.f, 0.f, 0.f, 0.f}, s1 = {0.f, 0.f, 0.f, 0.f};
    int e = beg;
    for (; e + 2 <= end; e += 2) {
        const int2 A = sc[e];
        const int2 B = sc[e + 1];
        const uint2 xa = e2b[A.x * 16 + d4];
        const uint2 xc = e2b[B.x * 16 + d4];
        fma4(s0, __int_as_float(A.y), bfunpack4(xa));
        fma4(s1, __int_as_float(B.y), bfunpack4(xc));
    }
    if (e < end) {
        const int2 A = sc[e];
        fma4(s0, __int_as_float(A.y), bfunpack4(e2b[A.x * 16 + d4]));
    }
    const int o = row * 16 + d4;
    const float4 g  = ego4_at(ue4, ie4, row, d4);
    const float4 a1 = bfunpack4(e1b[o]);
    const float4 a2 = bfunpack4(e2b[o]);
    float4 r;
    r.x = (g.x + a1.x + a2.x + s0.x + s1.x) * 0.25f;
    r.y = (g.y + a1.y + a2.y + s0.y + s1.y) * 0.25f;
    r.z = (g.z + a1.z + a2.z + s0.z + s1.z) * 0.25f;
    r.w = (g.w + a1.w + a2.w + s0.w + s1.w) * 0.25f;
    out4[o] = r;
}

// ---------------- fallback (round-1 proven path) ----------------
__global__ void lgcn_init(const float4* __restrict__ ue, const float4* __restrict__ ie,
                          float4* __restrict__ cur, float4* __restrict__ acc) {
    const long total  = (long)N_NODES * (DIM / 4);
    const long utotal = (long)NUM_USER * (DIM / 4);
    long i = (long)blockIdx.x * blockDim.x + threadIdx.x;
    const long stride = (long)gridDim.x * blockDim.x;
    for (; i < total; i += stride) {
        float4 v = (i < utotal) ? ue[i] : ie[i - utotal];
        cur[i] = v;
        acc[i] = v;
    }
}

__global__ void lgcn_spmm_atomic(const int* __restrict__ rows, const int* __restrict__ cols,
                                 const float* __restrict__ vals, const float* __restrict__ x,
                                 float* __restrict__ y) {
    const long total  = (long)NNZ * DIM;
    long t = (long)blockIdx.x * blockDim.x + threadIdx.x;
    const long stride = (long)gridDim.x * blockDim.x;
    for (; t < total; t += stride) {
        const int e = (int)(t >> 6);
        const int d = (int)(t & 63);
        atomicAdd(&y[((long)rows[e] << 6) + d], vals[e] * x[((long)cols[e] << 6) + d]);
    }
}

__global__ void lgcn_add(float4* __restrict__ acc, const float4* __restrict__ nxt, float scale) {
    const long total  = (long)N_NODES * (DIM / 4);
    long i = (long)blockIdx.x * blockDim.x + threadIdx.x;
    const long stride = (long)gridDim.x * blockDim.x;
    for (; i < total; i += stride) {
        float4 a = acc[i];
        const float4 b = nxt[i];
        a.x = (a.x + b.x) * scale;
        a.y = (a.y + b.y) * scale;
        a.z = (a.z + b.z) * scale;
        a.w = (a.w + b.w) * scale;
        acc[i] = a;
    }
}

extern "C" void kernel_launch(void* const* d_in, const int* in_sizes, int n_in,
                              void* d_out, int out_size, void* d_ws, size_t ws_size,
                              hipStream_t stream) {
    const float* ue   = (const float*)d_in[0];
    const float* ie   = (const float*)d_in[1];
    const int*   rows = (const int*)d_in[2];
    const int*   cols = (const int*)d_in[3];
    const float* vals = (const float*)d_in[4];
    float* out = (float*)d_out;

    const size_t embBytes  = (size_t)N_NODES * DIM * sizeof(float);  // 134,217,728
    const size_t embBytesH = embBytes / 2;                           // 67,108,864
    char* ws = (char*)d_ws;
    uint2* e1b = (uint2*)ws;                                         // 67 MB
    uint2* e2b = (uint2*)(ws + embBytesH);                           // 67 MB
    char* p = ws + 2 * embBytesH;
    int2* sc = (int2*)p;                 p += (size_t)NNZ * 8;       // 10 MB
    int2* eb = (int2*)p;                 p += (size_t)NNZ * 8;       // 10 MB
    unsigned short* ebrow = (unsigned short*)p; p += (size_t)NNZ * 2;// 2.5 MB
    int* row_ptr = (int*)p;              p += (size_t)(N_NODES + 1) * 4;
    int* bcnt    = (int*)p;              p += (size_t)NBUCK * PB_BLOCKS * 4;  // 512 KB
    int* tot     = (int*)p;              p += (size_t)NBUCK * 4;
    int* bbase   = (int*)p;              p += (size_t)(NBUCK + 1) * 4;
    const size_t need = (size_t)(p - ws);

    if (ws_size >= need) {
        // ---- histogram-free bucketed CSR build + edge sort ----
        bucket_count   <<<PB_BLOCKS, 256, 0, stream>>>(rows, bcnt);
        scan_bcnt      <<<NBUCK,     256, 0, stream>>>(bcnt, tot);
        scan_btot      <<<1,         256, 0, stream>>>(tot, bbase);
        bucket_scatter <<<PB_BLOCKS, 256, 0, stream>>>(rows, cols, vals, bcnt, bbase,
                                                       eb, ebrow);
        bucket_finalize<<<NBUCK,     256, 0, stream>>>(bbase, eb, ebrow, row_ptr, sc);

        // ---- 3 layers; mean fused into layer 3 ----
        const int grid = N_NODES / ROWS_PER_BLOCK;                   // 32768
        spmm_first<<<grid, 256, 0, stream>>>(row_ptr, sc,
                                             (const float4*)ue, (const float4*)ie, e1b);
        spmm_b2b  <<<grid, 256, 0, stream>>>(row_ptr, sc, e1b, e2b);
        spmm_last <<<grid, 256, 0, stream>>>(row_ptr, sc,
                                             (const float4*)ue, (const float4*)ie,
                                             e1b, e2b, (float4*)out);
    } else {
        // ---- fallback: round-1 proven path (needs 2*embBytes) ----
        float* buf0 = (float*)ws;
        float* buf1 = (float*)(ws + embBytes);
        lgcn_init<<<4096, 256, 0, stream>>>((const float4*)ue, (const float4*)ie,
                                            (float4*)buf0, (float4*)out);
        float* cur = buf0;
        float* nxt = buf1;
        for (int l = 0; l < 3; ++l) {
            hipMemsetAsync(nxt, 0, embBytes, stream);
            lgcn_spmm_atomic<<<2048, 256, 0, stream>>>(rows, cols, vals, cur, nxt);
            const float scale = (l == 2) ? 0.25f : 1.0f;
            lgcn_add<<<4096, 256, 0, stream>>>((float4*)out, (const float4*)nxt, scale);
            float* t = cur; cur = nxt; nxt = t;
        }
    }
}

// Round 8
// 284.259 us; speedup vs baseline: 3.9342x; 1.0909x over previous
//
#include <hip/hip_runtime.h>

// LightGCN propagation on MI355X — bf16 states, bucketed CSR, 8-lane bf16 rows.
// R7 lesson: traffic is near structural minimum; spmm runs at 3.2/6.3 TB/s —
// concurrency-limited. R8: bf16-gather kernels use 8 lanes/row (uint4 = 16B
// per lane), 8 rows/wave -> 16 outstanding 128B gathers per wave (unroll 2),
// half the waves, half the instructions. spmm_first keeps 16 lanes (f32 rows).

constexpr int NUM_USER = 262144;
constexpr int NUM_ITEM = 262144;
constexpr int DIM      = 64;
constexpr int N_NODES  = NUM_USER + NUM_ITEM;   // 524288
constexpr int NNZ      = 1250000;

constexpr int NBUCK = 256;                      // bucket = row >> 11
constexpr int ROWS_PER_BUCK = N_NODES / NBUCK;  // 2048
constexpr int PB_BLOCKS = 512;
constexpr int CHUNK = (NNZ + PB_BLOCKS - 1) / PB_BLOCKS;  // 2442
constexpr int BCAP = 6144;                      // bucket mean 4883, sd ~70

// ---------------- bf16 pack/unpack (RNE) ----------------
__device__ __forceinline__ unsigned bfpack2(float a, float b) {
    unsigned ua = __float_as_uint(a); ua += 0x7fffu + ((ua >> 16) & 1u);
    unsigned ub = __float_as_uint(b); ub += 0x7fffu + ((ub >> 16) & 1u);
    return (ua >> 16) | (ub & 0xffff0000u);
}
__device__ __forceinline__ uint2 bfpack4(float4 v) {
    return make_uint2(bfpack2(v.x, v.y), bfpack2(v.z, v.w));
}
__device__ __forceinline__ uint4 bfpack8(float4 a, float4 b) {
    return make_uint4(bfpack2(a.x, a.y), bfpack2(a.z, a.w),
                      bfpack2(b.x, b.y), bfpack2(b.z, b.w));
}
__device__ __forceinline__ void bfunpack8(uint4 u, float4& l, float4& h) {
    l.x = __uint_as_float(u.x << 16);
    l.y = __uint_as_float(u.x & 0xffff0000u);
    l.z = __uint_as_float(u.y << 16);
    l.w = __uint_as_float(u.y & 0xffff0000u);
    h.x = __uint_as_float(u.z << 16);
    h.y = __uint_as_float(u.z & 0xffff0000u);
    h.z = __uint_as_float(u.w << 16);
    h.w = __uint_as_float(u.w & 0xffff0000u);
}
__device__ __forceinline__ void fma4(float4& s, float v, const float4 x) {
    s.x = fmaf(v, x.x, s.x);
    s.y = fmaf(v, x.y, s.y);
    s.z = fmaf(v, x.z, s.z);
    s.w = fmaf(v, x.w, s.w);
}
__device__ __forceinline__ float4 ego4_at(const float4* __restrict__ ue4,
                                          const float4* __restrict__ ie4,
                                          int node, int d4) {
    return (node < NUM_USER) ? ue4[node * 16 + d4]
                             : ie4[(node - NUM_USER) * 16 + d4];
}

// ---------------- bucket pipeline (unchanged from R7) ----------------
__global__ void bucket_count(const int* __restrict__ rows, int* __restrict__ bcnt) {
    __shared__ int lcnt[NBUCK];
    const int t = threadIdx.x;
    lcnt[t] = 0;
    __syncthreads();
    const int beg = blockIdx.x * CHUNK;
    const int end = min(beg + CHUNK, NNZ);
    for (int i = beg + t; i < end; i += 256)
        atomicAdd(&lcnt[rows[i] >> 11], 1);
    __syncthreads();
    bcnt[t * PB_BLOCKS + blockIdx.x] = lcnt[t];
}

__global__ void scan_bcnt(int* __restrict__ bcnt, int* __restrict__ tot) {
    __shared__ int tmp[256];
    const int b = blockIdx.x, t = threadIdx.x;
    const int a0 = bcnt[b * PB_BLOCKS + 2 * t];
    const int a1 = bcnt[b * PB_BLOCKS + 2 * t + 1];
    const int run = a0 + a1;
    tmp[t] = run;
    __syncthreads();
    for (int off = 1; off < 256; off <<= 1) {
        int x = (t >= off) ? tmp[t - off] : 0;
        __syncthreads();
        tmp[t] += x;
        __syncthreads();
    }
    const int excl = tmp[t] - run;
    bcnt[b * PB_BLOCKS + 2 * t]     = excl;
    bcnt[b * PB_BLOCKS + 2 * t + 1] = excl + a0;
    if (t == 255) tot[b] = tmp[255];
}

__global__ void scan_btot(const int* __restrict__ tot, int* __restrict__ bbase) {
    __shared__ int tmp[256];
    const int t = threadIdx.x;
    const int v = tot[t];
    tmp[t] = v;
    __syncthreads();
    for (int off = 1; off < 256; off <<= 1) {
        int x = (t >= off) ? tmp[t - off] : 0;
        __syncthreads();
        tmp[t] += x;
        __syncthreads();
    }
    bbase[t] = tmp[t] - v;
    if (t == 0) bbase[NBUCK] = NNZ;
}

__global__ void bucket_scatter(const int* __restrict__ rows, const int* __restrict__ cols,
                               const float* __restrict__ vals,
                               const int* __restrict__ bcnt, const int* __restrict__ bbase,
                               int2* __restrict__ eb, unsigned short* __restrict__ ebrow) {
    __shared__ int lbase[NBUCK];
    __shared__ int lofs[NBUCK];
    const int t = threadIdx.x;
    lbase[t] = bbase[t] + bcnt[t * PB_BLOCKS + blockIdx.x];
    lofs[t] = 0;
    __syncthreads();
    const int beg = blockIdx.x * CHUNK;
    const int end = min(beg + CHUNK, NNZ);
    for (int i = beg + t; i < end; i += 256) {
        const int r = rows[i];
        const int b = r >> 11;
        const int p = lbase[b] + atomicAdd(&lofs[b], 1);
        eb[p]    = make_int2(cols[i], __float_as_int(vals[i]));
        ebrow[p] = (unsigned short)(r & (ROWS_PER_BUCK - 1));
    }
}

__global__ void bucket_finalize(const int* __restrict__ bbase,
                                const int2* __restrict__ eb,
                                const unsigned short* __restrict__ ebrow,
                                int* __restrict__ row_ptr, int2* __restrict__ sc) {
    __shared__ int  lcnt[ROWS_PER_BUCK];
    __shared__ int  tmp[256];
    __shared__ int2 lout[BCAP];
    const int b    = blockIdx.x;
    const int t    = threadIdx.x;
    const int base = bbase[b];
    const int cnt  = bbase[b + 1] - base;
    for (int r = t; r < ROWS_PER_BUCK; r += 256) lcnt[r] = 0;
    __syncthreads();
    for (int i = t; i < cnt; i += 256)
        atomicAdd(&lcnt[ebrow[base + i]], 1);
    __syncthreads();
    int loc[8];
    int run = 0;
    #pragma unroll
    for (int k = 0; k < 8; ++k) { const int v = lcnt[t * 8 + k]; loc[k] = run; run += v; }
    tmp[t] = run;
    __syncthreads();
    for (int off = 1; off < 256; off <<= 1) {
        int x = (t >= off) ? tmp[t - off] : 0;
        __syncthreads();
        tmp[t] += x;
        __syncthreads();
    }
    const int excl = tmp[t] - run;
    #pragma unroll
    for (int k = 0; k < 8; ++k) lcnt[t * 8 + k] = loc[k] + excl;
    __syncthreads();
    for (int r = t; r < ROWS_PER_BUCK; r += 256)
        row_ptr[b * ROWS_PER_BUCK + r] = base + lcnt[r];
    if (b == NBUCK - 1 && t == 0) row_ptr[N_NODES] = NNZ;
    __syncthreads();
    if (cnt <= BCAP) {
        for (int i = t; i < cnt; i += 256) {
            const int p = atomicAdd(&lcnt[ebrow[base + i]], 1);
            lout[p] = eb[base + i];
        }
        __syncthreads();
        for (int i = t; i < cnt; i += 256)
            sc[base + i] = lout[i];
    } else {
        for (int i = t; i < cnt; i += 256) {
            const int p = atomicAdd(&lcnt[ebrow[base + i]], 1);
            sc[base + p] = eb[base + i];
        }
    }
}

// ---------------- SpMM layers ----------------
// layer 1: 16 lanes/row (f32 256B gathers from ue/ie), writes bf16 e1
__global__ void spmm_first(const int* __restrict__ ptr, const int2* __restrict__ sc,
                           const float4* __restrict__ ue4, const float4* __restrict__ ie4,
                           uint2* __restrict__ e1b) {
    const int row = blockIdx.x * 16 + (threadIdx.x >> 4);
    const int d4  = threadIdx.x & 15;
    const int beg = ptr[row];
    const int end = ptr[row + 1];
    float4 s0 = {0.f, 0.f, 0.f, 0.f}, s1 = {0.f, 0.f, 0.f, 0.f};
    int e = beg;
    for (; e + 2 <= end; e += 2) {
        const int2 A = sc[e];
        const int2 B = sc[e + 1];
        fma4(s0, __int_as_float(A.y), ego4_at(ue4, ie4, A.x, d4));
        fma4(s1, __int_as_float(B.y), ego4_at(ue4, ie4, B.x, d4));
    }
    if (e < end) {
        const int2 A = sc[e];
        fma4(s0, __int_as_float(A.y), ego4_at(ue4, ie4, A.x, d4));
    }
    s0.x += s1.x; s0.y += s1.y; s0.z += s1.z; s0.w += s1.w;
    e1b[row * 16 + d4] = bfpack4(s0);
}

// layer 2: 8 lanes/row (uint4 = 16B/lane), 8 rows/wave, 32 rows/block
__global__ void spmm_b2b(const int* __restrict__ ptr, const int2* __restrict__ sc,
                         const uint4* __restrict__ xb, uint4* __restrict__ yb) {
    const int row = blockIdx.x * 32 + (threadIdx.x >> 3);
    const int d8  = threadIdx.x & 7;
    const int beg = ptr[row];
    const int end = ptr[row + 1];
    float4 a0 = {0.f,0.f,0.f,0.f}, b0 = {0.f,0.f,0.f,0.f};
    float4 a1 = {0.f,0.f,0.f,0.f}, b1 = {0.f,0.f,0.f,0.f};
    int e = beg;
    for (; e + 2 <= end; e += 2) {
        const int2 A = sc[e];
        const int2 B = sc[e + 1];
        const uint4 xa = xb[A.x * 8 + d8];
        const uint4 xc = xb[B.x * 8 + d8];
        float4 l, h;
        bfunpack8(xa, l, h);
        fma4(a0, __int_as_float(A.y), l); fma4(b0, __int_as_float(A.y), h);
        bfunpack8(xc, l, h);
        fma4(a1, __int_as_float(B.y), l); fma4(b1, __int_as_float(B.y), h);
    }
    if (e < end) {
        const int2 A = sc[e];
        float4 l, h;
        bfunpack8(xb[A.x * 8 + d8], l, h);
        fma4(a0, __int_as_float(A.y), l); fma4(b0, __int_as_float(A.y), h);
    }
    a0.x += a1.x; a0.y += a1.y; a0.z += a1.z; a0.w += a1.w;
    b0.x += b1.x; b0.y += b1.y; b0.z += b1.z; b0.w += b1.w;
    yb[row * 8 + d8] = bfpack8(a0, b0);
}

// layer 3: 8 lanes/row; e3 in regs; out = (ego_f32 + e1 + e2 + e3) / 4
__global__ void spmm_last(const int* __restrict__ ptr, const int2* __restrict__ sc,
                          const float4* __restrict__ ue4, const float4* __restrict__ ie4,
                          const uint4* __restrict__ e1b, const uint4* __restrict__ e2b,
                          float4* __restrict__ out4) {
    const int row = blockIdx.x * 32 + (threadIdx.x >> 3);
    const int d8  = threadIdx.x & 7;
    const int beg = ptr[row];
    const int end = ptr[row + 1];
    float4 a0 = {0.f,0.f,0.f,0.f}, b0 = {0.f,0.f,0.f,0.f};
    float4 a1 = {0.f,0.f,0.f,0.f}, b1 = {0.f,0.f,0.f,0.f};
    int e = beg;
    for (; e + 2 <= end; e += 2) {
        const int2 A = sc[e];
        const int2 B = sc[e + 1];
        const uint4 xa = e2b[A.x * 8 + d8];
        const uint4 xc = e2b[B.x * 8 + d8];
        float4 l, h;
        bfunpack8(xa, l, h);
        fma4(a0, __int_as_float(A.y), l); fma4(b0, __int_as_float(A.y), h);
        bfunpack8(xc, l, h);
        fma4(a1, __int_as_float(B.y), l); fma4(b1, __int_as_float(B.y), h);
    }
    if (e < end) {
        const int2 A = sc[e];
        float4 l, h;
        bfunpack8(e2b[A.x * 8 + d8], l, h);
        fma4(a0, __int_as_float(A.y), l); fma4(b0, __int_as_float(A.y), h);
    }
    a0.x += a1.x; a0.y += a1.y; a0.z += a1.z; a0.w += a1.w;
    b0.x += b1.x; b0.y += b1.y; b0.z += b1.z; b0.w += b1.w;
    // epilogue: dims [8*d8 .. 8*d8+7]
    const int o8 = row * 8 + d8;
    float4 l1, h1, l2, h2;
    bfunpack8(e1b[o8], l1, h1);
    bfunpack8(e2b[o8], l2, h2);
    const float4 gl = ego4_at(ue4, ie4, row, 2 * d8);
    const float4 gh = ego4_at(ue4, ie4, row, 2 * d8 + 1);
    float4 r0, r1;
    r0.x = (gl.x + l1.x + l2.x + a0.x) * 0.25f;
    r0.y = (gl.y + l1.y + l2.y + a0.y) * 0.25f;
    r0.z = (gl.z + l1.z + l2.z + a0.z) * 0.25f;
    r0.w = (gl.w + l1.w + l2.w + a0.w) * 0.25f;
    r1.x = (gh.x + h1.x + h2.x + b0.x) * 0.25f;
    r1.y = (gh.y + h1.y + h2.y + b0.y) * 0.25f;
    r1.z = (gh.z + h1.z + h2.z + b0.z) * 0.25f;
    r1.w = (gh.w + h1.w + h2.w + b0.w) * 0.25f;
    out4[row * 16 + 2 * d8]     = r0;
    out4[row * 16 + 2 * d8 + 1] = r1;
}

// ---------------- fallback (round-1 proven path) ----------------
__global__ void lgcn_init(const float4* __restrict__ ue, const float4* __restrict__ ie,
                          float4* __restrict__ cur, float4* __restrict__ acc) {
    const long total  = (long)N_NODES * (DIM / 4);
    const long utotal = (long)NUM_USER * (DIM / 4);
    long i = (long)blockIdx.x * blockDim.x + threadIdx.x;
    const long stride = (long)gridDim.x * blockDim.x;
    for (; i < total; i += stride) {
        float4 v = (i < utotal) ? ue[i] : ie[i - utotal];
        cur[i] = v;
        acc[i] = v;
    }
}

__global__ void lgcn_spmm_atomic(const int* __restrict__ rows, const int* __restrict__ cols,
                                 const float* __restrict__ vals, const float* __restrict__ x,
                                 float* __restrict__ y) {
    const long total  = (long)NNZ * DIM;
    long t = (long)blockIdx.x * blockDim.x + threadIdx.x;
    const long stride = (long)gridDim.x * blockDim.x;
    for (; t < total; t += stride) {
        const int e = (int)(t >> 6);
        const int d = (int)(t & 63);
        atomicAdd(&y[((long)rows[e] << 6) + d], vals[e] * x[((long)cols[e] << 6) + d]);
    }
}

__global__ void lgcn_add(float4* __restrict__ acc, const float4* __restrict__ nxt, float scale) {
    const long total  = (long)N_NODES * (DIM / 4);
    long i = (long)blockIdx.x * blockDim.x + threadIdx.x;
    const long stride = (long)gridDim.x * blockDim.x;
    for (; i < total; i += stride) {
        float4 a = acc[i];
        const float4 b = nxt[i];
        a.x = (a.x + b.x) * scale;
        a.y = (a.y + b.y) * scale;
        a.z = (a.z + b.z) * scale;
        a.w = (a.w + b.w) * scale;
        acc[i] = a;
    }
}

extern "C" void kernel_launch(void* const* d_in, const int* in_sizes, int n_in,
                              void* d_out, int out_size, void* d_ws, size_t ws_size,
                              hipStream_t stream) {
    const float* ue   = (const float*)d_in[0];
    const float* ie   = (const float*)d_in[1];
    const int*   rows = (const int*)d_in[2];
    const int*   cols = (const int*)d_in[3];
    const float* vals = (const float*)d_in[4];
    float* out = (float*)d_out;

    const size_t embBytes  = (size_t)N_NODES * DIM * sizeof(float);  // 134,217,728
    const size_t embBytesH = embBytes / 2;                           // 67,108,864
    char* ws = (char*)d_ws;
    uint4* e1b = (uint4*)ws;                                         // 67 MB
    uint4* e2b = (uint4*)(ws + embBytesH);                           // 67 MB
    char* p = ws + 2 * embBytesH;
    int2* sc = (int2*)p;                 p += (size_t)NNZ * 8;       // 10 MB
    int2* eb = (int2*)p;                 p += (size_t)NNZ * 8;       // 10 MB
    unsigned short* ebrow = (unsigned short*)p; p += (size_t)NNZ * 2;// 2.5 MB
    int* row_ptr = (int*)p;              p += (size_t)(N_NODES + 1) * 4;
    int* bcnt    = (int*)p;              p += (size_t)NBUCK * PB_BLOCKS * 4;  // 512 KB
    int* tot     = (int*)p;              p += (size_t)NBUCK * 4;
    int* bbase   = (int*)p;              p += (size_t)(NBUCK + 1) * 4;
    const size_t need = (size_t)(p - ws);

    if (ws_size >= need) {
        // ---- histogram-free bucketed CSR build + edge sort ----
        bucket_count   <<<PB_BLOCKS, 256, 0, stream>>>(rows, bcnt);
        scan_bcnt      <<<NBUCK,     256, 0, stream>>>(bcnt, tot);
        scan_btot      <<<1,         256, 0, stream>>>(tot, bbase);
        bucket_scatter <<<PB_BLOCKS, 256, 0, stream>>>(rows, cols, vals, bcnt, bbase,
                                                       eb, ebrow);
        bucket_finalize<<<NBUCK,     256, 0, stream>>>(bbase, eb, ebrow, row_ptr, sc);

        // ---- 3 layers; mean fused into layer 3 ----
        spmm_first<<<N_NODES / 16, 256, 0, stream>>>(row_ptr, sc,
                                                     (const float4*)ue, (const float4*)ie,
                                                     (uint2*)e1b);
        spmm_b2b  <<<N_NODES / 32, 256, 0, stream>>>(row_ptr, sc, e1b, e2b);
        spmm_last <<<N_NODES / 32, 256, 0, stream>>>(row_ptr, sc,
                                                     (const float4*)ue, (const float4*)ie,
                                                     e1b, e2b, (float4*)out);
    } else {
        // ---- fallback: round-1 proven path (needs 2*embBytes) ----
        float* buf0 = (float*)ws;
        float* buf1 = (float*)(ws + embBytes);
        lgcn_init<<<4096, 256, 0, stream>>>((const float4*)ue, (const float4*)ie,
                                            (float4*)buf0, (float4*)out);
        float* cur = buf0;
        float* nxt = buf1;
        for (int l = 0; l < 3; ++l) {
            hipMemsetAsync(nxt, 0, embBytes, stream);
            lgcn_spmm_atomic<<<2048, 256, 0, stream>>>(rows, cols, vals, cur, nxt);
            const float scale = (l == 2) ? 0.25f : 1.0f;
            lgcn_add<<<4096, 256, 0, stream>>>((float4*)out, (const float4*)nxt, scale);
            float* t = cur; cur = nxt; nxt = t;
        }
    }
}

// Round 9
// 273.915 us; speedup vs baseline: 4.0828x; 1.0378x over previous
//
#include <hip/hip_runtime.h>

// LightGCN propagation on MI355X — bf16 states, bucketed CSR, max-MLP SpMM.
// R8 lesson: more edge chains per wave = higher achieved BW (8-lane bf16
// kernels dropped out of top-5). R9: apply uniformly — spmm_first goes 8
// lanes/row (2x float4 per lane, 8 chains/wave); bf16 kernels go 4 lanes/row
// (2x uint4 per lane, 16 chains/wave). Arithmetic per dim unchanged.

constexpr int NUM_USER = 262144;
constexpr int NUM_ITEM = 262144;
constexpr int DIM      = 64;
constexpr int N_NODES  = NUM_USER + NUM_ITEM;   // 524288
constexpr int NNZ      = 1250000;

constexpr int NBUCK = 256;                      // bucket = row >> 11
constexpr int ROWS_PER_BUCK = N_NODES / NBUCK;  // 2048
constexpr int PB_BLOCKS = 512;
constexpr int CHUNK = (NNZ + PB_BLOCKS - 1) / PB_BLOCKS;  // 2442
constexpr int BCAP = 6144;                      // bucket mean 4883, sd ~70

// ---------------- bf16 pack/unpack (RNE) ----------------
__device__ __forceinline__ unsigned bfpack2(float a, float b) {
    unsigned ua = __float_as_uint(a); ua += 0x7fffu + ((ua >> 16) & 1u);
    unsigned ub = __float_as_uint(b); ub += 0x7fffu + ((ub >> 16) & 1u);
    return (ua >> 16) | (ub & 0xffff0000u);
}
__device__ __forceinline__ uint4 bfpack8(float4 a, float4 b) {
    return make_uint4(bfpack2(a.x, a.y), bfpack2(a.z, a.w),
                      bfpack2(b.x, b.y), bfpack2(b.z, b.w));
}
__device__ __forceinline__ void bfunpack8(uint4 u, float4& l, float4& h) {
    l.x = __uint_as_float(u.x << 16);
    l.y = __uint_as_float(u.x & 0xffff0000u);
    l.z = __uint_as_float(u.y << 16);
    l.w = __uint_as_float(u.y & 0xffff0000u);
    h.x = __uint_as_float(u.z << 16);
    h.y = __uint_as_float(u.z & 0xffff0000u);
    h.z = __uint_as_float(u.w << 16);
    h.w = __uint_as_float(u.w & 0xffff0000u);
}
__device__ __forceinline__ void fma4(float4& s, float v, const float4 x) {
    s.x = fmaf(v, x.x, s.x);
    s.y = fmaf(v, x.y, s.y);
    s.z = fmaf(v, x.z, s.z);
    s.w = fmaf(v, x.w, s.w);
}
__device__ __forceinline__ float4 add4(float4 a, float4 b) {
    return make_float4(a.x + b.x, a.y + b.y, a.z + b.z, a.w + b.w);
}

// ---------------- bucket pipeline (unchanged from R7) ----------------
__global__ void bucket_count(const int* __restrict__ rows, int* __restrict__ bcnt) {
    __shared__ int lcnt[NBUCK];
    const int t = threadIdx.x;
    lcnt[t] = 0;
    __syncthreads();
    const int beg = blockIdx.x * CHUNK;
    const int end = min(beg + CHUNK, NNZ);
    for (int i = beg + t; i < end; i += 256)
        atomicAdd(&lcnt[rows[i] >> 11], 1);
    __syncthreads();
    bcnt[t * PB_BLOCKS + blockIdx.x] = lcnt[t];
}

__global__ void scan_bcnt(int* __restrict__ bcnt, int* __restrict__ tot) {
    __shared__ int tmp[256];
    const int b = blockIdx.x, t = threadIdx.x;
    const int a0 = bcnt[b * PB_BLOCKS + 2 * t];
    const int a1 = bcnt[b * PB_BLOCKS + 2 * t + 1];
    const int run = a0 + a1;
    tmp[t] = run;
    __syncthreads();
    for (int off = 1; off < 256; off <<= 1) {
        int x = (t >= off) ? tmp[t - off] : 0;
        __syncthreads();
        tmp[t] += x;
        __syncthreads();
    }
    const int excl = tmp[t] - run;
    bcnt[b * PB_BLOCKS + 2 * t]     = excl;
    bcnt[b * PB_BLOCKS + 2 * t + 1] = excl + a0;
    if (t == 255) tot[b] = tmp[255];
}

__global__ void scan_btot(const int* __restrict__ tot, int* __restrict__ bbase) {
    __shared__ int tmp[256];
    const int t = threadIdx.x;
    const int v = tot[t];
    tmp[t] = v;
    __syncthreads();
    for (int off = 1; off < 256; off <<= 1) {
        int x = (t >= off) ? tmp[t - off] : 0;
        __syncthreads();
        tmp[t] += x;
        __syncthreads();
    }
    bbase[t] = tmp[t] - v;
    if (t == 0) bbase[NBUCK] = NNZ;
}

__global__ void bucket_scatter(const int* __restrict__ rows, const int* __restrict__ cols,
                               const float* __restrict__ vals,
                               const int* __restrict__ bcnt, const int* __restrict__ bbase,
                               int2* __restrict__ eb, unsigned short* __restrict__ ebrow) {
    __shared__ int lbase[NBUCK];
    __shared__ int lofs[NBUCK];
    const int t = threadIdx.x;
    lbase[t] = bbase[t] + bcnt[t * PB_BLOCKS + blockIdx.x];
    lofs[t] = 0;
    __syncthreads();
    const int beg = blockIdx.x * CHUNK;
    const int end = min(beg + CHUNK, NNZ);
    for (int i = beg + t; i < end; i += 256) {
        const int r = rows[i];
        const int b = r >> 11;
        const int p = lbase[b] + atomicAdd(&lofs[b], 1);
        eb[p]    = make_int2(cols[i], __float_as_int(vals[i]));
        ebrow[p] = (unsigned short)(r & (ROWS_PER_BUCK - 1));
    }
}

__global__ void bucket_finalize(const int* __restrict__ bbase,
                                const int2* __restrict__ eb,
                                const unsigned short* __restrict__ ebrow,
                                int* __restrict__ row_ptr, int2* __restrict__ sc) {
    __shared__ int  lcnt[ROWS_PER_BUCK];
    __shared__ int  tmp[256];
    __shared__ int2 lout[BCAP];
    const int b    = blockIdx.x;
    const int t    = threadIdx.x;
    const int base = bbase[b];
    const int cnt  = bbase[b + 1] - base;
    for (int r = t; r < ROWS_PER_BUCK; r += 256) lcnt[r] = 0;
    __syncthreads();
    for (int i = t; i < cnt; i += 256)
        atomicAdd(&lcnt[ebrow[base + i]], 1);
    __syncthreads();
    int loc[8];
    int run = 0;
    #pragma unroll
    for (int k = 0; k < 8; ++k) { const int v = lcnt[t * 8 + k]; loc[k] = run; run += v; }
    tmp[t] = run;
    __syncthreads();
    for (int off = 1; off < 256; off <<= 1) {
        int x = (t >= off) ? tmp[t - off] : 0;
        __syncthreads();
        tmp[t] += x;
        __syncthreads();
    }
    const int excl = tmp[t] - run;
    #pragma unroll
    for (int k = 0; k < 8; ++k) lcnt[t * 8 + k] = loc[k] + excl;
    __syncthreads();
    for (int r = t; r < ROWS_PER_BUCK; r += 256)
        row_ptr[b * ROWS_PER_BUCK + r] = base + lcnt[r];
    if (b == NBUCK - 1 && t == 0) row_ptr[N_NODES] = NNZ;
    __syncthreads();
    if (cnt <= BCAP) {
        for (int i = t; i < cnt; i += 256) {
            const int p = atomicAdd(&lcnt[ebrow[base + i]], 1);
            lout[p] = eb[base + i];
        }
        __syncthreads();
        for (int i = t; i < cnt; i += 256)
            sc[base + i] = lout[i];
    } else {
        for (int i = t; i < cnt; i += 256) {
            const int p = atomicAdd(&lcnt[ebrow[base + i]], 1);
            sc[base + p] = eb[base + i];
        }
    }
}

// ---------------- SpMM layers ----------------
// layer 1: 8 lanes/row, 2x float4 per lane (f32 gathers), writes bf16 e1
__global__ void spmm_first(const int* __restrict__ ptr, const int2* __restrict__ sc,
                           const float4* __restrict__ ue4, const float4* __restrict__ ie4,
                           uint4* __restrict__ e1b) {
    const int row = blockIdx.x * 32 + (threadIdx.x >> 3);
    const int d8  = threadIdx.x & 7;
    const int beg = ptr[row];
    const int end = ptr[row + 1];
    float4 a0 = {0.f,0.f,0.f,0.f}, b0 = {0.f,0.f,0.f,0.f};
    float4 a1 = {0.f,0.f,0.f,0.f}, b1 = {0.f,0.f,0.f,0.f};
    int e = beg;
    for (; e + 2 <= end; e += 2) {
        const int2 A = sc[e];
        const int2 B = sc[e + 1];
        const float4* pa = (A.x < NUM_USER) ? ue4 + (size_t)A.x * 16
                                            : ie4 + (size_t)(A.x - NUM_USER) * 16;
        const float4* pb = (B.x < NUM_USER) ? ue4 + (size_t)B.x * 16
                                            : ie4 + (size_t)(B.x - NUM_USER) * 16;
        const float4 al = pa[2 * d8], ah = pa[2 * d8 + 1];
        const float4 bl = pb[2 * d8], bh = pb[2 * d8 + 1];
        const float va = __int_as_float(A.y);
        const float vb = __int_as_float(B.y);
        fma4(a0, va, al); fma4(b0, va, ah);
        fma4(a1, vb, bl); fma4(b1, vb, bh);
    }
    if (e < end) {
        const int2 A = sc[e];
        const float4* pa = (A.x < NUM_USER) ? ue4 + (size_t)A.x * 16
                                            : ie4 + (size_t)(A.x - NUM_USER) * 16;
        const float va = __int_as_float(A.y);
        fma4(a0, va, pa[2 * d8]); fma4(b0, va, pa[2 * d8 + 1]);
    }
    e1b[row * 8 + d8] = bfpack8(add4(a0, a1), add4(b0, b1));
}

// layer 2: 4 lanes/row, 2x uint4 per lane (16 dims/lane), 16 rows/wave
__global__ void spmm_b2b(const int* __restrict__ ptr, const int2* __restrict__ sc,
                         const uint4* __restrict__ xb, uint4* __restrict__ yb) {
    const int row = blockIdx.x * 64 + (threadIdx.x >> 2);
    const int d4  = threadIdx.x & 3;
    const int beg = ptr[row];
    const int end = ptr[row + 1];
    float4 p0 = {0.f,0.f,0.f,0.f}, q0 = {0.f,0.f,0.f,0.f};
    float4 r0 = {0.f,0.f,0.f,0.f}, s0 = {0.f,0.f,0.f,0.f};
    float4 p1 = {0.f,0.f,0.f,0.f}, q1 = {0.f,0.f,0.f,0.f};
    float4 r1 = {0.f,0.f,0.f,0.f}, s1 = {0.f,0.f,0.f,0.f};
    int e = beg;
    for (; e + 2 <= end; e += 2) {
        const int2 A = sc[e];
        const int2 B = sc[e + 1];
        const uint4 xa0 = xb[A.x * 8 + 2 * d4];
        const uint4 xa1 = xb[A.x * 8 + 2 * d4 + 1];
        const uint4 xb0 = xb[B.x * 8 + 2 * d4];
        const uint4 xb1 = xb[B.x * 8 + 2 * d4 + 1];
        const float va = __int_as_float(A.y);
        const float vb = __int_as_float(B.y);
        float4 l, h;
        bfunpack8(xa0, l, h); fma4(p0, va, l); fma4(q0, va, h);
        bfunpack8(xa1, l, h); fma4(r0, va, l); fma4(s0, va, h);
        bfunpack8(xb0, l, h); fma4(p1, vb, l); fma4(q1, vb, h);
        bfunpack8(xb1, l, h); fma4(r1, vb, l); fma4(s1, vb, h);
    }
    if (e < end) {
        const int2 A = sc[e];
        const float va = __int_as_float(A.y);
        float4 l, h;
        bfunpack8(xb[A.x * 8 + 2 * d4], l, h);     fma4(p0, va, l); fma4(q0, va, h);
        bfunpack8(xb[A.x * 8 + 2 * d4 + 1], l, h); fma4(r0, va, l); fma4(s0, va, h);
    }
    yb[row * 8 + 2 * d4]     = bfpack8(add4(p0, p1), add4(q0, q1));
    yb[row * 8 + 2 * d4 + 1] = bfpack8(add4(r0, r1), add4(s0, s1));
}

// layer 3: 4 lanes/row; e3 in regs; out = (ego_f32 + e1 + e2 + e3) / 4
__global__ void spmm_last(const int* __restrict__ ptr, const int2* __restrict__ sc,
                          const float4* __restrict__ ue4, const float4* __restrict__ ie4,
                          const uint4* __restrict__ e1b, const uint4* __restrict__ e2b,
                          float4* __restrict__ out4) {
    const int row = blockIdx.x * 64 + (threadIdx.x >> 2);
    const int d4  = threadIdx.x & 3;
    const int beg = ptr[row];
    const int end = ptr[row + 1];
    float4 p0 = {0.f,0.f,0.f,0.f}, q0 = {0.f,0.f,0.f,0.f};
    float4 r0 = {0.f,0.f,0.f,0.f}, s0 = {0.f,0.f,0.f,0.f};
    float4 p1 = {0.f,0.f,0.f,0.f}, q1 = {0.f,0.f,0.f,0.f};
    float4 r1 = {0.f,0.f,0.f,0.f}, s1 = {0.f,0.f,0.f,0.f};
    int e = beg;
    for (; e + 2 <= end; e += 2) {
        const int2 A = sc[e];
        const int2 B = sc[e + 1];
        const uint4 xa0 = e2b[A.x * 8 + 2 * d4];
        const uint4 xa1 = e2b[A.x * 8 + 2 * d4 + 1];
        const uint4 xb0 = e2b[B.x * 8 + 2 * d4];
        const uint4 xb1 = e2b[B.x * 8 + 2 * d4 + 1];
        const float va = __int_as_float(A.y);
        const float vb = __int_as_float(B.y);
        float4 l, h;
        bfunpack8(xa0, l, h); fma4(p0, va, l); fma4(q0, va, h);
        bfunpack8(xa1, l, h); fma4(r0, va, l); fma4(s0, va, h);
        bfunpack8(xb0, l, h); fma4(p1, vb, l); fma4(q1, vb, h);
        bfunpack8(xb1, l, h); fma4(r1, vb, l); fma4(s1, vb, h);
    }
    if (e < end) {
        const int2 A = sc[e];
        const float va = __int_as_float(A.y);
        float4 l, h;
        bfunpack8(e2b[A.x * 8 + 2 * d4], l, h);     fma4(p0, va, l); fma4(q0, va, h);
        bfunpack8(e2b[A.x * 8 + 2 * d4 + 1], l, h); fma4(r0, va, l); fma4(s0, va, h);
    }
    // epilogue: dims [16*d4 .. 16*d4+15]
    const int o8 = row * 8 + 2 * d4;
    float4 l1a, h1a, l1b, h1b, l2a, h2a, l2b, h2b;
    bfunpack8(e1b[o8], l1a, h1a);
    bfunpack8(e1b[o8 + 1], l1b, h1b);
    bfunpack8(e2b[o8], l2a, h2a);
    bfunpack8(e2b[o8 + 1], l2b, h2b);
    const float4* pg = (row < NUM_USER) ? ue4 + (size_t)row * 16
                                        : ie4 + (size_t)(row - NUM_USER) * 16;
    const float4 g0 = pg[4 * d4], g1 = pg[4 * d4 + 1];
    const float4 g2 = pg[4 * d4 + 2], g3 = pg[4 * d4 + 3];
    float4 o0, o1, o2, o3;
    o0.x = (g0.x + l1a.x + l2a.x + p0.x + p1.x) * 0.25f;
    o0.y = (g0.y + l1a.y + l2a.y + p0.y + p1.y) * 0.25f;
    o0.z = (g0.z + l1a.z + l2a.z + p0.z + p1.z) * 0.25f;
    o0.w = (g0.w + l1a.w + l2a.w + p0.w + p1.w) * 0.25f;
    o1.x = (g1.x + h1a.x + h2a.x + q0.x + q1.x) * 0.25f;
    o1.y = (g1.y + h1a.y + h2a.y + q0.y + q1.y) * 0.25f;
    o1.z = (g1.z + h1a.z + h2a.z + q0.z + q1.z) * 0.25f;
    o1.w = (g1.w + h1a.w + h2a.w + q0.w + q1.w) * 0.25f;
    o2.x = (g2.x + l1b.x + l2b.x + r0.x + r1.x) * 0.25f;
    o2.y = (g2.y + l1b.y + l2b.y + r0.y + r1.y) * 0.25f;
    o2.z = (g2.z + l1b.z + l2b.z + r0.z + r1.z) * 0.25f;
    o2.w = (g2.w + l1b.w + l2b.w + r0.w + r1.w) * 0.25f;
    o3.x = (g3.x + h1b.x + h2b.x + s0.x + s1.x) * 0.25f;
    o3.y = (g3.y + h1b.y + h2b.y + s0.y + s1.y) * 0.25f;
    o3.z = (g3.z + h1b.z + h2b.z + s0.z + s1.z) * 0.25f;
    o3.w = (g3.w + h1b.w + h2b.w + s0.w + s1.w) * 0.25f;
    const int ob = row * 16 + 4 * d4;
    out4[ob]     = o0;
    out4[ob + 1] = o1;
    out4[ob + 2] = o2;
    out4[ob + 3] = o3;
}

// ---------------- fallback (round-1 proven path) ----------------
__global__ void lgcn_init(const float4* __restrict__ ue, const float4* __restrict__ ie,
                          float4* __restrict__ cur, float4* __restrict__ acc) {
    const long total  = (long)N_NODES * (DIM / 4);
    const long utotal = (long)NUM_USER * (DIM / 4);
    long i = (long)blockIdx.x * blockDim.x + threadIdx.x;
    const long stride = (long)gridDim.x * blockDim.x;
    for (; i < total; i += stride) {
        float4 v = (i < utotal) ? ue[i] : ie[i - utotal];
        cur[i] = v;
        acc[i] = v;
    }
}

__global__ void lgcn_spmm_atomic(const int* __restrict__ rows, const int* __restrict__ cols,
                                 const float* __restrict__ vals, const float* __restrict__ x,
                                 float* __restrict__ y) {
    const long total  = (long)NNZ * DIM;
    long t = (long)blockIdx.x * blockDim.x + threadIdx.x;
    const long stride = (long)gridDim.x * blockDim.x;
    for (; t < total; t += stride) {
        const int e = (int)(t >> 6);
        const int d = (int)(t & 63);
        atomicAdd(&y[((long)rows[e] << 6) + d], vals[e] * x[((long)cols[e] << 6) + d]);
    }
}

__global__ void lgcn_add(float4* __restrict__ acc, const float4* __restrict__ nxt, float scale) {
    const long total  = (long)N_NODES * (DIM / 4);
    long i = (long)blockIdx.x * blockDim.x + threadIdx.x;
    const long stride = (long)gridDim.x * blockDim.x;
    for (; i < total; i += stride) {
        float4 a = acc[i];
        const float4 b = nxt[i];
        a.x = (a.x + b.x) * scale;
        a.y = (a.y + b.y) * scale;
        a.z = (a.z + b.z) * scale;
        a.w = (a.w + b.w) * scale;
        acc[i] = a;
    }
}

extern "C" void kernel_launch(void* const* d_in, const int* in_sizes, int n_in,
                              void* d_out, int out_size, void* d_ws, size_t ws_size,
                              hipStream_t stream) {
    const float* ue   = (const float*)d_in[0];
    const float* ie   = (const float*)d_in[1];
    const int*   rows = (const int*)d_in[2];
    const int*   cols = (const int*)d_in[3];
    const float* vals = (const float*)d_in[4];
    float* out = (float*)d_out;

    const size_t embBytes  = (size_t)N_NODES * DIM * sizeof(float);  // 134,217,728
    const size_t embBytesH = embBytes / 2;                           // 67,108,864
    char* ws = (char*)d_ws;
    uint4* e1b = (uint4*)ws;                                         // 67 MB
    uint4* e2b = (uint4*)(ws + embBytesH);                           // 67 MB
    char* p = ws + 2 * embBytesH;
    int2* sc = (int2*)p;                 p += (size_t)NNZ * 8;       // 10 MB
    int2* eb = (int2*)p;                 p += (size_t)NNZ * 8;       // 10 MB
    unsigned short* ebrow = (unsigned short*)p; p += (size_t)NNZ * 2;// 2.5 MB
    int* row_ptr = (int*)p;              p += (size_t)(N_NODES + 1) * 4;
    int* bcnt    = (int*)p;              p += (size_t)NBUCK * PB_BLOCKS * 4;  // 512 KB
    int* tot     = (int*)p;              p += (size_t)NBUCK * 4;
    int* bbase   = (int*)p;              p += (size_t)(NBUCK + 1) * 4;
    const size_t need = (size_t)(p - ws);

    if (ws_size >= need) {
        // ---- histogram-free bucketed CSR build + edge sort ----
        bucket_count   <<<PB_BLOCKS, 256, 0, stream>>>(rows, bcnt);
        scan_bcnt      <<<NBUCK,     256, 0, stream>>>(bcnt, tot);
        scan_btot      <<<1,         256, 0, stream>>>(tot, bbase);
        bucket_scatter <<<PB_BLOCKS, 256, 0, stream>>>(rows, cols, vals, bcnt, bbase,
                                                       eb, ebrow);
        bucket_finalize<<<NBUCK,     256, 0, stream>>>(bbase, eb, ebrow, row_ptr, sc);

        // ---- 3 layers; mean fused into layer 3 ----
        spmm_first<<<N_NODES / 32, 256, 0, stream>>>(row_ptr, sc,
                                                     (const float4*)ue, (const float4*)ie,
                                                     e1b);
        spmm_b2b  <<<N_NODES / 64, 256, 0, stream>>>(row_ptr, sc, e1b, e2b);
        spmm_last <<<N_NODES / 64, 256, 0, stream>>>(row_ptr, sc,
                                                     (const float4*)ue, (const float4*)ie,
                                                     e1b, e2b, (float4*)out);
    } else {
        // ---- fallback: round-1 proven path (needs 2*embBytes) ----
        float* buf0 = (float*)ws;
        float* buf1 = (float*)(ws + embBytes);
        lgcn_init<<<4096, 256, 0, stream>>>((const float4*)ue, (const float4*)ie,
                                            (float4*)buf0, (float4*)out);
        float* cur = buf0;
        float* nxt = buf1;
        for (int l = 0; l < 3; ++l) {
            hipMemsetAsync(nxt, 0, embBytes, stream);
            lgcn_spmm_atomic<<<2048, 256, 0, stream>>>(rows, cols, vals, cur, nxt);
            const float scale = (l == 2) ? 0.25f : 1.0f;
            lgcn_add<<<4096, 256, 0, stream>>>((float4*)out, (const float4*)nxt, scale);
            float* t = cur; cur = nxt; nxt = t;
        }
    }
}

// Round 10
// 262.982 us; speedup vs baseline: 4.2526x; 1.0416x over previous
//
#include <hip/hip_runtime.h>

// LightGCN propagation on MI355X — bf16 states, bucketed CSR, 8-lane SpMM.
// R9 lesson: 4 lanes/row regressed spmm_last (VGPR 40, occ 54%) — 8 lanes is
// the sweet spot for 128B bf16 rows. R10: all three spmm kernels at 8
// lanes/row; spmm_last hoists its 4 coalesced epilogue loads BEFORE the edge
// loop so they overlap the latency-bound gather chain.

constexpr int NUM_USER = 262144;
constexpr int NUM_ITEM = 262144;
constexpr int DIM      = 64;
constexpr int N_NODES  = NUM_USER + NUM_ITEM;   // 524288
constexpr int NNZ      = 1250000;

constexpr int NBUCK = 256;                      // bucket = row >> 11
constexpr int ROWS_PER_BUCK = N_NODES / NBUCK;  // 2048
constexpr int PB_BLOCKS = 512;
constexpr int CHUNK = (NNZ + PB_BLOCKS - 1) / PB_BLOCKS;  // 2442
constexpr int BCAP = 6144;                      // bucket mean 4883, sd ~70

// ---------------- bf16 pack/unpack (RNE) ----------------
__device__ __forceinline__ unsigned bfpack2(float a, float b) {
    unsigned ua = __float_as_uint(a); ua += 0x7fffu + ((ua >> 16) & 1u);
    unsigned ub = __float_as_uint(b); ub += 0x7fffu + ((ub >> 16) & 1u);
    return (ua >> 16) | (ub & 0xffff0000u);
}
__device__ __forceinline__ uint4 bfpack8(float4 a, float4 b) {
    return make_uint4(bfpack2(a.x, a.y), bfpack2(a.z, a.w),
                      bfpack2(b.x, b.y), bfpack2(b.z, b.w));
}
__device__ __forceinline__ void bfunpack8(uint4 u, float4& l, float4& h) {
    l.x = __uint_as_float(u.x << 16);
    l.y = __uint_as_float(u.x & 0xffff0000u);
    l.z = __uint_as_float(u.y << 16);
    l.w = __uint_as_float(u.y & 0xffff0000u);
    h.x = __uint_as_float(u.z << 16);
    h.y = __uint_as_float(u.z & 0xffff0000u);
    h.z = __uint_as_float(u.w << 16);
    h.w = __uint_as_float(u.w & 0xffff0000u);
}
__device__ __forceinline__ void fma4(float4& s, float v, const float4 x) {
    s.x = fmaf(v, x.x, s.x);
    s.y = fmaf(v, x.y, s.y);
    s.z = fmaf(v, x.z, s.z);
    s.w = fmaf(v, x.w, s.w);
}
__device__ __forceinline__ float4 add4(float4 a, float4 b) {
    return make_float4(a.x + b.x, a.y + b.y, a.z + b.z, a.w + b.w);
}

// ---------------- bucket pipeline (unchanged from R7) ----------------
__global__ void bucket_count(const int* __restrict__ rows, int* __restrict__ bcnt) {
    __shared__ int lcnt[NBUCK];
    const int t = threadIdx.x;
    lcnt[t] = 0;
    __syncthreads();
    const int beg = blockIdx.x * CHUNK;
    const int end = min(beg + CHUNK, NNZ);
    for (int i = beg + t; i < end; i += 256)
        atomicAdd(&lcnt[rows[i] >> 11], 1);
    __syncthreads();
    bcnt[t * PB_BLOCKS + blockIdx.x] = lcnt[t];
}

__global__ void scan_bcnt(int* __restrict__ bcnt, int* __restrict__ tot) {
    __shared__ int tmp[256];
    const int b = blockIdx.x, t = threadIdx.x;
    const int a0 = bcnt[b * PB_BLOCKS + 2 * t];
    const int a1 = bcnt[b * PB_BLOCKS + 2 * t + 1];
    const int run = a0 + a1;
    tmp[t] = run;
    __syncthreads();
    for (int off = 1; off < 256; off <<= 1) {
        int x = (t >= off) ? tmp[t - off] : 0;
        __syncthreads();
        tmp[t] += x;
        __syncthreads();
    }
    const int excl = tmp[t] - run;
    bcnt[b * PB_BLOCKS + 2 * t]     = excl;
    bcnt[b * PB_BLOCKS + 2 * t + 1] = excl + a0;
    if (t == 255) tot[b] = tmp[255];
}

__global__ void scan_btot(const int* __restrict__ tot, int* __restrict__ bbase) {
    __shared__ int tmp[256];
    const int t = threadIdx.x;
    const int v = tot[t];
    tmp[t] = v;
    __syncthreads();
    for (int off = 1; off < 256; off <<= 1) {
        int x = (t >= off) ? tmp[t - off] : 0;
        __syncthreads();
        tmp[t] += x;
        __syncthreads();
    }
    bbase[t] = tmp[t] - v;
    if (t == 0) bbase[NBUCK] = NNZ;
}

__global__ void bucket_scatter(const int* __restrict__ rows, const int* __restrict__ cols,
                               const float* __restrict__ vals,
                               const int* __restrict__ bcnt, const int* __restrict__ bbase,
                               int2* __restrict__ eb, unsigned short* __restrict__ ebrow) {
    __shared__ int lbase[NBUCK];
    __shared__ int lofs[NBUCK];
    const int t = threadIdx.x;
    lbase[t] = bbase[t] + bcnt[t * PB_BLOCKS + blockIdx.x];
    lofs[t] = 0;
    __syncthreads();
    const int beg = blockIdx.x * CHUNK;
    const int end = min(beg + CHUNK, NNZ);
    for (int i = beg + t; i < end; i += 256) {
        const int r = rows[i];
        const int b = r >> 11;
        const int p = lbase[b] + atomicAdd(&lofs[b], 1);
        eb[p]    = make_int2(cols[i], __float_as_int(vals[i]));
        ebrow[p] = (unsigned short)(r & (ROWS_PER_BUCK - 1));
    }
}

__global__ void bucket_finalize(const int* __restrict__ bbase,
                                const int2* __restrict__ eb,
                                const unsigned short* __restrict__ ebrow,
                                int* __restrict__ row_ptr, int2* __restrict__ sc) {
    __shared__ int  lcnt[ROWS_PER_BUCK];
    __shared__ int  tmp[256];
    __shared__ int2 lout[BCAP];
    const int b    = blockIdx.x;
    const int t    = threadIdx.x;
    const int base = bbase[b];
    const int cnt  = bbase[b + 1] - base;
    for (int r = t; r < ROWS_PER_BUCK; r += 256) lcnt[r] = 0;
    __syncthreads();
    for (int i = t; i < cnt; i += 256)
        atomicAdd(&lcnt[ebrow[base + i]], 1);
    __syncthreads();
    int loc[8];
    int run = 0;
    #pragma unroll
    for (int k = 0; k < 8; ++k) { const int v = lcnt[t * 8 + k]; loc[k] = run; run += v; }
    tmp[t] = run;
    __syncthreads();
    for (int off = 1; off < 256; off <<= 1) {
        int x = (t >= off) ? tmp[t - off] : 0;
        __syncthreads();
        tmp[t] += x;
        __syncthreads();
    }
    const int excl = tmp[t] - run;
    #pragma unroll
    for (int k = 0; k < 8; ++k) lcnt[t * 8 + k] = loc[k] + excl;
    __syncthreads();
    for (int r = t; r < ROWS_PER_BUCK; r += 256)
        row_ptr[b * ROWS_PER_BUCK + r] = base + lcnt[r];
    if (b == NBUCK - 1 && t == 0) row_ptr[N_NODES] = NNZ;
    __syncthreads();
    if (cnt <= BCAP) {
        for (int i = t; i < cnt; i += 256) {
            const int p = atomicAdd(&lcnt[ebrow[base + i]], 1);
            lout[p] = eb[base + i];
        }
        __syncthreads();
        for (int i = t; i < cnt; i += 256)
            sc[base + i] = lout[i];
    } else {
        for (int i = t; i < cnt; i += 256) {
            const int p = atomicAdd(&lcnt[ebrow[base + i]], 1);
            sc[base + p] = eb[base + i];
        }
    }
}

// ---------------- SpMM layers (all 8 lanes/row, 8 rows/wave) ----------------
// layer 1: f32 gathers from ue/ie (2x float4 per lane), writes bf16 e1
__global__ void spmm_first(const int* __restrict__ ptr, const int2* __restrict__ sc,
                           const float4* __restrict__ ue4, const float4* __restrict__ ie4,
                           uint4* __restrict__ e1b) {
    const int row = blockIdx.x * 32 + (threadIdx.x >> 3);
    const int d8  = threadIdx.x & 7;
    const int beg = ptr[row];
    const int end = ptr[row + 1];
    float4 a0 = {0.f,0.f,0.f,0.f}, b0 = {0.f,0.f,0.f,0.f};
    float4 a1 = {0.f,0.f,0.f,0.f}, b1 = {0.f,0.f,0.f,0.f};
    int e = beg;
    for (; e + 2 <= end; e += 2) {
        const int2 A = sc[e];
        const int2 B = sc[e + 1];
        const float4* pa = (A.x < NUM_USER) ? ue4 + (size_t)A.x * 16
                                            : ie4 + (size_t)(A.x - NUM_USER) * 16;
        const float4* pb = (B.x < NUM_USER) ? ue4 + (size_t)B.x * 16
                                            : ie4 + (size_t)(B.x - NUM_USER) * 16;
        const float4 al = pa[2 * d8], ah = pa[2 * d8 + 1];
        const float4 bl = pb[2 * d8], bh = pb[2 * d8 + 1];
        const float va = __int_as_float(A.y);
        const float vb = __int_as_float(B.y);
        fma4(a0, va, al); fma4(b0, va, ah);
        fma4(a1, vb, bl); fma4(b1, vb, bh);
    }
    if (e < end) {
        const int2 A = sc[e];
        const float4* pa = (A.x < NUM_USER) ? ue4 + (size_t)A.x * 16
                                            : ie4 + (size_t)(A.x - NUM_USER) * 16;
        const float va = __int_as_float(A.y);
        fma4(a0, va, pa[2 * d8]); fma4(b0, va, pa[2 * d8 + 1]);
    }
    e1b[row * 8 + d8] = bfpack8(add4(a0, a1), add4(b0, b1));
}

// layer 2: bf16 gathers (uint4 per lane)
__global__ void spmm_b2b(const int* __restrict__ ptr, const int2* __restrict__ sc,
                         const uint4* __restrict__ xb, uint4* __restrict__ yb) {
    const int row = blockIdx.x * 32 + (threadIdx.x >> 3);
    const int d8  = threadIdx.x & 7;
    const int beg = ptr[row];
    const int end = ptr[row + 1];
    float4 a0 = {0.f,0.f,0.f,0.f}, b0 = {0.f,0.f,0.f,0.f};
    float4 a1 = {0.f,0.f,0.f,0.f}, b1 = {0.f,0.f,0.f,0.f};
    int e = beg;
    for (; e + 2 <= end; e += 2) {
        const int2 A = sc[e];
        const int2 B = sc[e + 1];
        const uint4 xa = xb[A.x * 8 + d8];
        const uint4 xc = xb[B.x * 8 + d8];
        float4 l, h;
        bfunpack8(xa, l, h);
        fma4(a0, __int_as_float(A.y), l); fma4(b0, __int_as_float(A.y), h);
        bfunpack8(xc, l, h);
        fma4(a1, __int_as_float(B.y), l); fma4(b1, __int_as_float(B.y), h);
    }
    if (e < end) {
        const int2 A = sc[e];
        float4 l, h;
        bfunpack8(xb[A.x * 8 + d8], l, h);
        fma4(a0, __int_as_float(A.y), l); fma4(b0, __int_as_float(A.y), h);
    }
    yb[row * 8 + d8] = bfpack8(add4(a0, a1), add4(b0, b1));
}

// layer 3: e3 in regs; out = (ego_f32 + e1 + e2 + e3)/4.
// Epilogue stream loads hoisted BEFORE the edge loop to overlap the gathers.
__global__ void spmm_last(const int* __restrict__ ptr, const int2* __restrict__ sc,
                          const float4* __restrict__ ue4, const float4* __restrict__ ie4,
                          const uint4* __restrict__ e1b, const uint4* __restrict__ e2b,
                          float4* __restrict__ out4) {
    const int row = blockIdx.x * 32 + (threadIdx.x >> 3);
    const int d8  = threadIdx.x & 7;
    const int beg = ptr[row];
    const int end = ptr[row + 1];
    // hoisted epilogue loads (coalesced; in flight during the edge loop)
    const int o8 = row * 8 + d8;
    const float4* pg = (row < NUM_USER) ? ue4 + (size_t)row * 16
                                        : ie4 + (size_t)(row - NUM_USER) * 16;
    const float4 gl = pg[2 * d8];
    const float4 gh = pg[2 * d8 + 1];
    const uint4 u1 = e1b[o8];
    const uint4 u2 = e2b[o8];
    float4 a0 = {0.f,0.f,0.f,0.f}, b0 = {0.f,0.f,0.f,0.f};
    float4 a1 = {0.f,0.f,0.f,0.f}, b1 = {0.f,0.f,0.f,0.f};
    int e = beg;
    for (; e + 2 <= end; e += 2) {
        const int2 A = sc[e];
        const int2 B = sc[e + 1];
        const uint4 xa = e2b[A.x * 8 + d8];
        const uint4 xc = e2b[B.x * 8 + d8];
        float4 l, h;
        bfunpack8(xa, l, h);
        fma4(a0, __int_as_float(A.y), l); fma4(b0, __int_as_float(A.y), h);
        bfunpack8(xc, l, h);
        fma4(a1, __int_as_float(B.y), l); fma4(b1, __int_as_float(B.y), h);
    }
    if (e < end) {
        const int2 A = sc[e];
        float4 l, h;
        bfunpack8(e2b[A.x * 8 + d8], l, h);
        fma4(a0, __int_as_float(A.y), l); fma4(b0, __int_as_float(A.y), h);
    }
    a0 = add4(a0, a1); b0 = add4(b0, b1);
    float4 l1, h1, l2, h2;
    bfunpack8(u1, l1, h1);
    bfunpack8(u2, l2, h2);
    float4 r0, r1;
    r0.x = (gl.x + l1.x + l2.x + a0.x) * 0.25f;
    r0.y = (gl.y + l1.y + l2.y + a0.y) * 0.25f;
    r0.z = (gl.z + l1.z + l2.z + a0.z) * 0.25f;
    r0.w = (gl.w + l1.w + l2.w + a0.w) * 0.25f;
    r1.x = (gh.x + h1.x + h2.x + b0.x) * 0.25f;
    r1.y = (gh.y + h1.y + h2.y + b0.y) * 0.25f;
    r1.z = (gh.z + h1.z + h2.z + b0.z) * 0.25f;
    r1.w = (gh.w + h1.w + h2.w + b0.w) * 0.25f;
    out4[row * 16 + 2 * d8]     = r0;
    out4[row * 16 + 2 * d8 + 1] = r1;
}

// ---------------- fallback (round-1 proven path) ----------------
__global__ void lgcn_init(const float4* __restrict__ ue, const float4* __restrict__ ie,
                          float4* __restrict__ cur, float4* __restrict__ acc) {
    const long total  = (long)N_NODES * (DIM / 4);
    const long utotal = (long)NUM_USER * (DIM / 4);
    long i = (long)blockIdx.x * blockDim.x + threadIdx.x;
    const long stride = (long)gridDim.x * blockDim.x;
    for (; i < total; i += stride) {
        float4 v = (i < utotal) ? ue[i] : ie[i - utotal];
        cur[i] = v;
        acc[i] = v;
    }
}

__global__ void lgcn_spmm_atomic(const int* __restrict__ rows, const int* __restrict__ cols,
                                 const float* __restrict__ vals, const float* __restrict__ x,
                                 float* __restrict__ y) {
    const long total  = (long)NNZ * DIM;
    long t = (long)blockIdx.x * blockDim.x + threadIdx.x;
    const long stride = (long)gridDim.x * blockDim.x;
    for (; t < total; t += stride) {
        const int e = (int)(t >> 6);
        const int d = (int)(t & 63);
        atomicAdd(&y[((long)rows[e] << 6) + d], vals[e] * x[((long)cols[e] << 6) + d]);
    }
}

__global__ void lgcn_add(float4* __restrict__ acc, const float4* __restrict__ nxt, float scale) {
    const long total  = (long)N_NODES * (DIM / 4);
    long i = (long)blockIdx.x * blockDim.x + threadIdx.x;
    const long stride = (long)gridDim.x * blockDim.x;
    for (; i < total; i += stride) {
        float4 a = acc[i];
        const float4 b = nxt[i];
        a.x = (a.x + b.x) * scale;
        a.y = (a.y + b.y) * scale;
        a.z = (a.z + b.z) * scale;
        a.w = (a.w + b.w) * scale;
        acc[i] = a;
    }
}

extern "C" void kernel_launch(void* const* d_in, const int* in_sizes, int n_in,
                              void* d_out, int out_size, void* d_ws, size_t ws_size,
                              hipStream_t stream) {
    const float* ue   = (const float*)d_in[0];
    const float* ie   = (const float*)d_in[1];
    const int*   rows = (const int*)d_in[2];
    const int*   cols = (const int*)d_in[3];
    const float* vals = (const float*)d_in[4];
    float* out = (float*)d_out;

    const size_t embBytes  = (size_t)N_NODES * DIM * sizeof(float);  // 134,217,728
    const size_t embBytesH = embBytes / 2;                           // 67,108,864
    char* ws = (char*)d_ws;
    uint4* e1b = (uint4*)ws;                                         // 67 MB
    uint4* e2b = (uint4*)(ws + embBytesH);                           // 67 MB
    char* p = ws + 2 * embBytesH;
    int2* sc = (int2*)p;                 p += (size_t)NNZ * 8;       // 10 MB
    int2* eb = (int2*)p;                 p += (size_t)NNZ * 8;       // 10 MB
    unsigned short* ebrow = (unsigned short*)p; p += (size_t)NNZ * 2;// 2.5 MB
    int* row_ptr = (int*)p;              p += (size_t)(N_NODES + 1) * 4;
    int* bcnt    = (int*)p;              p += (size_t)NBUCK * PB_BLOCKS * 4;  // 512 KB
    int* tot     = (int*)p;              p += (size_t)NBUCK * 4;
    int* bbase   = (int*)p;              p += (size_t)(NBUCK + 1) * 4;
    const size_t need = (size_t)(p - ws);

    if (ws_size >= need) {
        // ---- histogram-free bucketed CSR build + edge sort ----
        bucket_count   <<<PB_BLOCKS, 256, 0, stream>>>(rows, bcnt);
        scan_bcnt      <<<NBUCK,     256, 0, stream>>>(bcnt, tot);
        scan_btot      <<<1,         256, 0, stream>>>(tot, bbase);
        bucket_scatter <<<PB_BLOCKS, 256, 0, stream>>>(rows, cols, vals, bcnt, bbase,
                                                       eb, ebrow);
        bucket_finalize<<<NBUCK,     256, 0, stream>>>(bbase, eb, ebrow, row_ptr, sc);

        // ---- 3 layers; mean fused into layer 3 ----
        spmm_first<<<N_NODES / 32, 256, 0, stream>>>(row_ptr, sc,
                                                     (const float4*)ue, (const float4*)ie,
                                                     e1b);
        spmm_b2b  <<<N_NODES / 32, 256, 0, stream>>>(row_ptr, sc, e1b, e2b);
        spmm_last <<<N_NODES / 32, 256, 0, stream>>>(row_ptr, sc,
                                                     (const float4*)ue, (const float4*)ie,
                                                     e1b, e2b, (float4*)out);
    } else {
        // ---- fallback: round-1 proven path (needs 2*embBytes) ----
        float* buf0 = (float*)ws;
        float* buf1 = (float*)(ws + embBytes);
        lgcn_init<<<4096, 256, 0, stream>>>((const float4*)ue, (const float4*)ie,
                                            (float4*)buf0, (float4*)out);
        float* cur = buf0;
        float* nxt = buf1;
        for (int l = 0; l < 3; ++l) {
            hipMemsetAsync(nxt, 0, embBytes, stream);
            lgcn_spmm_atomic<<<2048, 256, 0, stream>>>(rows, cols, vals, cur, nxt);
            const float scale = (l == 2) ? 0.25f : 1.0f;
            lgcn_add<<<4096, 256, 0, stream>>>((float4*)out, (const float4*)nxt, scale);
            float* t = cur; cur = nxt; nxt = t;
        }
    }
}